// Round 5
// baseline (639.219 us; speedup 1.0000x reference)
//
#include <hip/hip_runtime.h>
#include <math.h>

#define NN 50000
#define NF 512
#define NHID 256
#define NCLASS 64
#define NHEADS 8

typedef __attribute__((ext_vector_type(8))) short bf16x8;
typedef __attribute__((ext_vector_type(4))) float f32x4;
typedef __attribute__((ext_vector_type(4))) unsigned int u32x4;
typedef __attribute__((ext_vector_type(2))) unsigned int u32x2;

static __device__ __forceinline__ unsigned short f2bf(float f) {
  unsigned int u = __float_as_uint(f);
  unsigned int r = (u + 0x7fffu + ((u >> 16) & 1u)) >> 16;
  return (unsigned short)r;
}
static __device__ __forceinline__ float bf2f(unsigned short u) {
  return __uint_as_float(((unsigned int)u) << 16);
}
static __device__ __forceinline__ float2 bfpair(unsigned int u) {
  return make_float2(__uint_as_float(u << 16), __uint_as_float(u & 0xffff0000u));
}

// ---- inline-asm gathers: compiler tracks zero vmem in hot loops ----
static __device__ __forceinline__ u32x4 gld128(const void* p) {
  u32x4 r;
  asm volatile("global_load_dwordx4 %0, %1, off"
               : "=v"(r) : "v"((unsigned long long)p));
  return r;
}
static __device__ __forceinline__ u32x2 gld64(const void* p) {
  u32x2 r;
  asm volatile("global_load_dwordx2 %0, %1, off"
               : "=v"(r) : "v"((unsigned long long)p));
  return r;
}
static __device__ __forceinline__ int gld32i(const void* p) {
  int r;
  asm volatile("global_load_dword %0, %1, off"
               : "=v"(r) : "v"((unsigned long long)p));
  return r;
}
static __device__ __forceinline__ float gld32f(const void* p) {
  float r;
  asm volatile("global_load_dword %0, %1, off"
               : "=v"(r) : "v"((unsigned long long)p));
  return r;
}
#define VMCNT0()                                        \
  do {                                                  \
    asm volatile("s_waitcnt vmcnt(0)" ::: "memory");    \
    __builtin_amdgcn_sched_barrier(0);                  \
  } while (0)

// ---------------- CSR build ----------------
__global__ void k_init_deg(int* deg) {
  int i = blockIdx.x * blockDim.x + threadIdx.x;
  if (i < NN) deg[i] = 1;  // self loop
}

__global__ void k_count(const int* __restrict__ dst, int E0, int* deg) {
  int i = blockIdx.x * blockDim.x + threadIdx.x;
  if (i < E0) atomicAdd(&deg[dst[i]], 1);
}

__global__ __launch_bounds__(1024) void k_scan(const int* __restrict__ deg, int* offs,
                                               int* cursor) {
  __shared__ int wbase[16];
  __shared__ int srun;
  int tid = threadIdx.x;
  int lane = tid & 63;
  int wv = tid >> 6;
  if (tid == 0) srun = 0;
  __syncthreads();
  for (int base = 0; base < NN; base += 4096) {
    int i = base + tid * 4;
    int4 v;
    if (i + 3 < NN) {
      v = *(const int4*)(deg + i);
    } else {
      v.x = (i + 0 < NN) ? deg[i + 0] : 0;
      v.y = (i + 1 < NN) ? deg[i + 1] : 0;
      v.z = (i + 2 < NN) ? deg[i + 2] : 0;
      v.w = (i + 3 < NN) ? deg[i + 3] : 0;
    }
    int tot = v.x + v.y + v.z + v.w;
    int s = tot;
    #pragma unroll
    for (int o = 1; o < 64; o <<= 1) {
      int t = __shfl_up(s, o);
      if (lane >= o) s += t;
    }
    if (lane == 63) wbase[wv] = s;
    __syncthreads();
    if (tid == 0) {
      int run = srun;
      #pragma unroll
      for (int w2 = 0; w2 < 16; w2++) {
        int t = wbase[w2];
        wbase[w2] = run;
        run += t;
      }
      srun = run;
    }
    __syncthreads();
    int p = wbase[wv] + s - tot;
    if (i + 0 < NN) { offs[i + 0] = p; cursor[i + 0] = p; p += v.x; }
    if (i + 1 < NN) { offs[i + 1] = p; cursor[i + 1] = p; p += v.y; }
    if (i + 2 < NN) { offs[i + 2] = p; cursor[i + 2] = p; p += v.z; }
    if (i + 3 < NN) { offs[i + 3] = p; cursor[i + 3] = p; }
  }
  __syncthreads();
  if (tid == 0) offs[NN] = srun;
}

__global__ void k_scatter(const int* __restrict__ src, const int* __restrict__ dst,
                          int E0, int* cursor, int* __restrict__ nbr) {
  int i = blockIdx.x * blockDim.x + threadIdx.x;
  if (i < E0) {
    int pos = atomicAdd(&cursor[dst[i]], 1);
    nbr[pos] = src[i];
  } else if (i < E0 + NN) {
    int v = i - E0;
    int pos = atomicAdd(&cursor[v], 1);
    nbr[pos] = v;
  }
}

// ---------------- casts ----------------
__global__ void k_castWt(const float* __restrict__ W, unsigned short* __restrict__ Wt,
                         int K, int cols) {
  int i = blockIdx.x * blockDim.x + threadIdx.x;
  if (i >= K * cols) return;
  int k = i / cols, c = i % cols;
  Wt[(size_t)c * K + k] = f2bf(W[i]);
}

__global__ void k_castWt_perm(const float* __restrict__ W, unsigned short* __restrict__ Wt,
                              int K) {
  int i = blockIdx.x * blockDim.x + threadIdx.x;
  if (i >= K * NHEADS * NCLASS) return;
  int k = i / (NHEADS * NCLASS);
  int rem = i % (NHEADS * NCLASS);
  int h = rem / NCLASS, c = rem % NCLASS;
  Wt[(size_t)(c * NHEADS + h) * K + k] = f2bf(W[i]);
}

// ---------------- bf16 MFMA GEMM, LDS-staged B, bf16 output ----------------
__global__ __launch_bounds__(256) void k_gemm_bf(const unsigned short* __restrict__ A,
                                                 const unsigned short* __restrict__ Bt,
                                                 unsigned short* __restrict__ C,
                                                 int rows, int K, int cols) {
  __shared__ unsigned short Bs[256 * 40];  // 20 KB
  int t = threadIdx.x;
  int wave = t >> 6, lane = t & 63;
  int quad = lane >> 4, sixt = lane & 15;
  int rb = blockIdx.x * 64 + (wave >> 1) * 32;
  int cw = (wave & 1) * 128;
  int cbw = blockIdx.y * 256 + cw;
  int r0 = rb + sixt, r1 = rb + 16 + sixt;
  const unsigned short* Ap0 = A + (size_t)(r0 < rows ? r0 : 0) * K + quad * 8;
  const unsigned short* Ap1 = A + (size_t)(r1 < rows ? r1 : 0) * K + quad * 8;
  const unsigned short* Bg = Bt + (size_t)(blockIdx.y * 256 + (t >> 2)) * K + (t & 3) * 8;
  const size_t BgStep = (size_t)64 * K;
  char* BsW = (char*)Bs + (t >> 2) * 80 + (t & 3) * 16;
  f32x4 acc0[8] = {}, acc1[8] = {};
  for (int k0 = 0; k0 < K; k0 += 32) {
    uint4 v0 = *(const uint4*)(Bg + k0);
    uint4 v1 = *(const uint4*)(Bg + BgStep + k0);
    uint4 v2 = *(const uint4*)(Bg + 2 * BgStep + k0);
    uint4 v3 = *(const uint4*)(Bg + 3 * BgStep + k0);
    bf16x8 a0 = *(const bf16x8*)(Ap0 + k0);
    bf16x8 a1 = *(const bf16x8*)(Ap1 + k0);
    *(uint4*)(BsW) = v0;
    *(uint4*)(BsW + 64 * 80) = v1;
    *(uint4*)(BsW + 128 * 80) = v2;
    *(uint4*)(BsW + 192 * 80) = v3;
    __syncthreads();
    #pragma unroll
    for (int g = 0; g < 8; g++) {
      bf16x8 b = *(const bf16x8*)((const char*)Bs + (cw + g * 16 + sixt) * 80 + quad * 16);
      acc0[g] = __builtin_amdgcn_mfma_f32_16x16x32_bf16(a0, b, acc0[g], 0, 0, 0);
      acc1[g] = __builtin_amdgcn_mfma_f32_16x16x32_bf16(a1, b, acc1[g], 0, 0, 0);
    }
    __syncthreads();
  }
  #pragma unroll
  for (int r = 0; r < 4; r++) {
    int row = rb + quad * 4 + r;
    if (row < rows) {
      unsigned short* out = C + (size_t)row * cols + cbw + sixt;
      #pragma unroll
      for (int g = 0; g < 8; g++) out[g * 16] = f2bf(acc0[g][r]);
    }
    int row2 = row + 16;
    if (row2 < rows) {
      unsigned short* out = C + (size_t)row2 * cols + cbw + sixt;
      #pragma unroll
      for (int g = 0; g < 8; g++) out[g * 16] = f2bf(acc1[g][r]);
    }
  }
}

// ---------------- same GEMM but A is f32, converted at load (fuses the x cast) -----
__global__ __launch_bounds__(256) void k_gemm_f32a(const float* __restrict__ A,
                                                   const unsigned short* __restrict__ Bt,
                                                   unsigned short* __restrict__ C,
                                                   int rows, int K, int cols) {
  __shared__ unsigned short Bs[256 * 40];  // 20 KB
  int t = threadIdx.x;
  int wave = t >> 6, lane = t & 63;
  int quad = lane >> 4, sixt = lane & 15;
  int rb = blockIdx.x * 64 + (wave >> 1) * 32;
  int cw = (wave & 1) * 128;
  int cbw = blockIdx.y * 256 + cw;
  int r0 = rb + sixt, r1 = rb + 16 + sixt;
  const float* Ap0 = A + (size_t)(r0 < rows ? r0 : 0) * K + quad * 8;
  const float* Ap1 = A + (size_t)(r1 < rows ? r1 : 0) * K + quad * 8;
  const unsigned short* Bg = Bt + (size_t)(blockIdx.y * 256 + (t >> 2)) * K + (t & 3) * 8;
  const size_t BgStep = (size_t)64 * K;
  char* BsW = (char*)Bs + (t >> 2) * 80 + (t & 3) * 16;
  f32x4 acc0[8] = {}, acc1[8] = {};
  for (int k0 = 0; k0 < K; k0 += 32) {
    uint4 v0 = *(const uint4*)(Bg + k0);
    uint4 v1 = *(const uint4*)(Bg + BgStep + k0);
    uint4 v2 = *(const uint4*)(Bg + 2 * BgStep + k0);
    uint4 v3 = *(const uint4*)(Bg + 3 * BgStep + k0);
    float4 a0lo = *(const float4*)(Ap0 + k0);
    float4 a0hi = *(const float4*)(Ap0 + k0 + 4);
    float4 a1lo = *(const float4*)(Ap1 + k0);
    float4 a1hi = *(const float4*)(Ap1 + k0 + 4);
    bf16x8 a0, a1;
    a0[0] = (short)f2bf(a0lo.x); a0[1] = (short)f2bf(a0lo.y);
    a0[2] = (short)f2bf(a0lo.z); a0[3] = (short)f2bf(a0lo.w);
    a0[4] = (short)f2bf(a0hi.x); a0[5] = (short)f2bf(a0hi.y);
    a0[6] = (short)f2bf(a0hi.z); a0[7] = (short)f2bf(a0hi.w);
    a1[0] = (short)f2bf(a1lo.x); a1[1] = (short)f2bf(a1lo.y);
    a1[2] = (short)f2bf(a1lo.z); a1[3] = (short)f2bf(a1lo.w);
    a1[4] = (short)f2bf(a1hi.x); a1[5] = (short)f2bf(a1hi.y);
    a1[6] = (short)f2bf(a1hi.z); a1[7] = (short)f2bf(a1hi.w);
    *(uint4*)(BsW) = v0;
    *(uint4*)(BsW + 64 * 80) = v1;
    *(uint4*)(BsW + 128 * 80) = v2;
    *(uint4*)(BsW + 192 * 80) = v3;
    __syncthreads();
    #pragma unroll
    for (int g = 0; g < 8; g++) {
      bf16x8 b = *(const bf16x8*)((const char*)Bs + (cw + g * 16 + sixt) * 80 + quad * 16);
      acc0[g] = __builtin_amdgcn_mfma_f32_16x16x32_bf16(a0, b, acc0[g], 0, 0, 0);
      acc1[g] = __builtin_amdgcn_mfma_f32_16x16x32_bf16(a1, b, acc1[g], 0, 0, 0);
    }
    __syncthreads();
  }
  #pragma unroll
  for (int r = 0; r < 4; r++) {
    int row = rb + quad * 4 + r;
    if (row < rows) {
      unsigned short* out = C + (size_t)row * cols + cbw + sixt;
      #pragma unroll
      for (int g = 0; g < 8; g++) out[g * 16] = f2bf(acc0[g][r]);
    }
    int row2 = row + 16;
    if (row2 < rows) {
      unsigned short* out = C + (size_t)row2 * cols + cbw + sixt;
      #pragma unroll
      for (int g = 0; g < 8; g++) out[g * 16] = f2bf(acc1[g][r]);
    }
  }
}

// ---------------- edge-score dots, contiguous layout (layer 1) ----------------
template <int C>
__global__ void k_escore_c(const unsigned short* __restrict__ h,
                           const float* __restrict__ asr, const float* __restrict__ ads,
                           float* __restrict__ es, float* __restrict__ ed) {
  int idx = blockIdx.x * blockDim.x + threadIdx.x;  // n*8 + head
  if (idx >= NN * NHEADS) return;
  int hd = idx & 7;
  const unsigned short* row = h + (size_t)idx * C;
  float s = 0.f, d = 0.f;
  #pragma unroll
  for (int c8 = 0; c8 < C / 8; c8++) {
    uint4 raw = *(const uint4*)(row + c8 * 8);
    float2 p0 = bfpair(raw.x), p1 = bfpair(raw.y), p2 = bfpair(raw.z), p3 = bfpair(raw.w);
    const float* as_ = asr + hd * C + c8 * 8;
    const float* ad_ = ads + hd * C + c8 * 8;
    s += p0.x * as_[0] + p0.y * as_[1] + p1.x * as_[2] + p1.y * as_[3] +
         p2.x * as_[4] + p2.y * as_[5] + p3.x * as_[6] + p3.y * as_[7];
    d += p0.x * ad_[0] + p0.y * ad_[1] + p1.x * ad_[2] + p1.y * ad_[3] +
         p2.x * ad_[4] + p2.y * ad_[5] + p3.x * ad_[6] + p3.y * ad_[7];
  }
  es[idx] = s;
  ed[idx] = d;
}

// ---------------- edge-score dots, permuted layout (layer 2), vectorized ----------
// Wave per node: lane = class (uint4 = 8 heads), butterfly all-reduce over classes,
// lane 0 stores the 16 per-head dots. Replaces 64 scalar stride-16B loads/thread.
__global__ __launch_bounds__(256) void k_escore_p2(const unsigned short* __restrict__ h,
                                                   const float* __restrict__ asr,
                                                   const float* __restrict__ ads,
                                                   float* __restrict__ es,
                                                   float* __restrict__ ed) {
  int node = blockIdx.x * 4 + (threadIdx.x >> 6);
  if (node >= NN) return;
  int lane = threadIdx.x & 63;  // class index
  uint4 raw = *(const uint4*)(h + (size_t)node * (NHEADS * NCLASS) + lane * 8);
  float2 p0 = bfpair(raw.x), p1 = bfpair(raw.y), p2 = bfpair(raw.z), p3 = bfpair(raw.w);
  float v[8] = {p0.x, p0.y, p1.x, p1.y, p2.x, p2.y, p3.x, p3.y};
  float s[8], d[8];
  #pragma unroll
  for (int hh = 0; hh < 8; hh++) {
    s[hh] = v[hh] * asr[hh * NCLASS + lane];
    d[hh] = v[hh] * ads[hh * NCLASS + lane];
  }
  #pragma unroll
  for (int o = 1; o < 64; o <<= 1) {
    #pragma unroll
    for (int hh = 0; hh < 8; hh++) {
      s[hh] += __shfl_xor(s[hh], o);
      d[hh] += __shfl_xor(d[hh], o);
    }
  }
  if (lane == 0) {
    #pragma unroll
    for (int hh = 0; hh < 8; hh++) {
      es[node * NHEADS + hh] = s[hh];
      ed[node * NHEADS + hh] = d[hh];
    }
  }
}

// ---------------- fused single-pass online-softmax + layer-1 aggregation ----------
// (round-3 validated structure)
__global__ __launch_bounds__(256) void k_agg1f(const int* __restrict__ offs,
                                               const int* __restrict__ nbr,
                                               const unsigned short* __restrict__ h1,
                                               const float* __restrict__ es,
                                               const float* __restrict__ ed,
                                               const float* __restrict__ b1,
                                               unsigned short* __restrict__ out) {
  int node = blockIdx.x * 4 + (threadIdx.x >> 6);
  if (node >= NN) return;
  int lane = threadIdx.x & 63;
  int h = lane & 7;
  int sub = lane >> 3;  // coef-phase edge slot; ALSO consume-phase head
  int col = lane << 2;  // consume-phase 4 channels
  int beg = offs[node], end = offs[node + 1];
  float edst = ed[node * NHEADS + h];
  int kb = beg;
  int iA = kb + (lane & 7); if (iA > end - 1) iA = end - 1;
  int vt = gld32i(nbr + iA);
  int vtN = 0;
  if (kb + 8 < end) {
    int iB = kb + 8 + (lane & 7); if (iB > end - 1) iB = end - 1;
    vtN = gld32i(nbr + iB);
  }
  VMCNT0();
  int se[8];
  #pragma unroll
  for (int e = 0; e < 8; e++) se[e] = __shfl(vt, e);
  float esv;
  {
    int sv = __shfl(vt, sub);
    esv = gld32f(es + (size_t)sv * NHEADS + h);
  }
  VMCNT0();
  float m = -1e30f, z = 0.f;
  float4 acc = make_float4(0.f, 0.f, 0.f, 0.f);
  while (true) {
    int cnt = end - kb; if (cnt > 8) cnt = 8;
    u32x2 r[8];
    #pragma unroll
    for (int e = 0; e < 8; e++)
      if (e < cnt) r[e] = gld64(h1 + (size_t)se[e] * NHID + col);
    bool more = kb + 8 < end, more2 = kb + 16 < end;
    int vt2 = 0;
    if (more2) {
      int iC = kb + 16 + (lane & 7); if (iC > end - 1) iC = end - 1;
      vt2 = gld32i(nbr + iC);
    }
    float esvN = 0.f;
    if (more) {
      int svN = __shfl(vtN, sub);
      esvN = gld32f(es + (size_t)svN * NHEADS + h);
    }
    // coef phase (overlaps in-flight gathers)
    float ar = esv + edst;
    ar = (ar > 0.f) ? ar : 0.2f * ar;
    float a = (kb + sub < end) ? ar : -1e30f;
    float gm = a;
    #pragma unroll
    for (int o = 8; o < 64; o <<= 1) gm = fmaxf(gm, __shfl_xor(gm, o));
    float mn = fmaxf(m, gm);
    float ee = __expf(a - mn);
    float zg = ee;
    #pragma unroll
    for (int o = 8; o < 64; o <<= 1) zg += __shfl_xor(zg, o);
    float sc = __expf(m - mn);
    z = z * sc + zg;
    m = mn;
    VMCNT0();
    // rescale + consume
    float sch = __shfl(sc, sub);
    acc.x *= sch; acc.y *= sch; acc.z *= sch; acc.w *= sch;
    #pragma unroll
    for (int e = 0; e < 8; e++) {
      if (e < cnt) {
        float ce = __shfl(ee, e * 8 + sub);  // lane 8e+head: edge e, head==sub
        float2 p0 = bfpair(r[e][0]), p1 = bfpair(r[e][1]);
        acc.x += ce * p0.x;
        acc.y += ce * p0.y;
        acc.z += ce * p1.x;
        acc.w += ce * p1.y;
      }
    }
    if (!more) break;
    kb += 8;
    #pragma unroll
    for (int e = 0; e < 8; e++) se[e] = __shfl(vtN, e);
    esv = esvN;
    vtN = vt2;
  }
  float inv = 1.f / z;
  float ivh = __shfl(inv, sub);
  ushort4 o;
  o.x = f2bf(fmaxf(acc.x * ivh + b1[col + 0], 0.f));
  o.y = f2bf(fmaxf(acc.y * ivh + b1[col + 1], 0.f));
  o.z = f2bf(fmaxf(acc.z * ivh + b1[col + 2], 0.f));
  o.w = f2bf(fmaxf(acc.w * ivh + b1[col + 3], 0.f));
  *(ushort4*)(out + (size_t)node * NHID + col) = o;
}

// ---------------- fused single-pass online-softmax + layer-2 agg + mean + lsm ------
// (round-3 validated structure)
__global__ __launch_bounds__(256) void k_agg2f(const int* __restrict__ offs,
                                               const int* __restrict__ nbr,
                                               const unsigned short* __restrict__ h2,
                                               const float* __restrict__ es,
                                               const float* __restrict__ ed,
                                               const float* __restrict__ b2,
                                               float* __restrict__ out) {
  __shared__ __align__(16) float cs[4][64];
  int wv = threadIdx.x >> 6;
  int node = blockIdx.x * 4 + wv;
  if (node >= NN) return;
  int lane = threadIdx.x & 63;
  int h = lane & 7;
  int sub = lane >> 3;
  int beg = offs[node], end = offs[node + 1];
  float edst = ed[node * NHEADS + h];
  int kb = beg;
  int iA = kb + (lane & 7); if (iA > end - 1) iA = end - 1;
  int vt = gld32i(nbr + iA);
  int vtN = 0;
  if (kb + 8 < end) {
    int iB = kb + 8 + (lane & 7); if (iB > end - 1) iB = end - 1;
    vtN = gld32i(nbr + iB);
  }
  VMCNT0();
  int se[8];
  #pragma unroll
  for (int e = 0; e < 8; e++) se[e] = __shfl(vt, e);
  float esv;
  {
    int sv = __shfl(vt, sub);
    esv = gld32f(es + (size_t)sv * NHEADS + h);
  }
  VMCNT0();
  float m = -1e30f, z = 0.f;
  float acc[8] = {};
  while (true) {
    int cnt = end - kb; if (cnt > 8) cnt = 8;
    u32x4 r[8];
    #pragma unroll
    for (int e = 0; e < 8; e++)
      if (e < cnt) r[e] = gld128(h2 + (size_t)se[e] * (NHEADS * NCLASS) + (lane << 3));
    bool more = kb + 8 < end, more2 = kb + 16 < end;
    int vt2 = 0;
    if (more2) {
      int iC = kb + 16 + (lane & 7); if (iC > end - 1) iC = end - 1;
      vt2 = gld32i(nbr + iC);
    }
    float esvN = 0.f;
    if (more) {
      int svN = __shfl(vtN, sub);
      esvN = gld32f(es + (size_t)svN * NHEADS + h);
    }
    // coef phase (overlaps in-flight gathers)
    float ar = esv + edst;
    ar = (ar > 0.f) ? ar : 0.2f * ar;
    float a = (kb + sub < end) ? ar : -1e30f;
    float gm = a;
    #pragma unroll
    for (int o = 8; o < 64; o <<= 1) gm = fmaxf(gm, __shfl_xor(gm, o));
    float mn = fmaxf(m, gm);
    float ee = __expf(a - mn);
    float zg = ee;
    #pragma unroll
    for (int o = 8; o < 64; o <<= 1) zg += __shfl_xor(zg, o);
    float sc = __expf(m - mn);
    z = z * sc + zg;
    m = mn;
    cs[wv][lane] = ee;  // per-wave staging, no barrier needed
    VMCNT0();
    // rescale + consume
    #pragma unroll
    for (int hh = 0; hh < 8; hh++) acc[hh] *= __shfl(sc, hh);
    #pragma unroll
    for (int e = 0; e < 8; e++) {
      if (e < cnt) {
        float4 cA = *(const float4*)&cs[wv][e * 8];
        float4 cB = *(const float4*)&cs[wv][e * 8 + 4];
        float2 p0 = bfpair(r[e][0]), p1 = bfpair(r[e][1]), p2 = bfpair(r[e][2]),
               p3 = bfpair(r[e][3]);
        acc[0] += cA.x * p0.x;
        acc[1] += cA.y * p0.y;
        acc[2] += cA.z * p1.x;
        acc[3] += cA.w * p1.y;
        acc[4] += cB.x * p2.x;
        acc[5] += cB.y * p2.y;
        acc[6] += cB.z * p3.x;
        acc[7] += cB.w * p3.y;
      }
    }
    if (!more) break;
    kb += 8;
    #pragma unroll
    for (int e = 0; e < 8; e++) se[e] = __shfl(vtN, e);
    esv = esvN;
    vtN = vt2;
  }
  float inv = 1.f / z;
  float val = 0.f;
  #pragma unroll
  for (int hh = 0; hh < 8; hh++) val += acc[hh] * __shfl(inv, hh);
  val = val * 0.125f + b2[lane];
  float mx = val;
  #pragma unroll
  for (int o = 32; o > 0; o >>= 1) mx = fmaxf(mx, __shfl_xor(mx, o));
  float ex = __expf(val - mx);
  float sm = ex;
  #pragma unroll
  for (int o = 32; o > 0; o >>= 1) sm += __shfl_xor(sm, o);
  out[(size_t)node * NCLASS + lane] = val - mx - __logf(sm);
}

// ---------------- launch ----------------
extern "C" void kernel_launch(void* const* d_in, const int* in_sizes, int n_in,
                              void* d_out, int out_size, void* d_ws, size_t ws_size,
                              hipStream_t stream) {
  const float* x   = (const float*)d_in[0];
  const int* eidx  = (const int*)d_in[1];
  const float* W1  = (const float*)d_in[2];
  const float* a1s = (const float*)d_in[3];
  const float* a1d = (const float*)d_in[4];
  const float* b1  = (const float*)d_in[5];
  const float* W2  = (const float*)d_in[6];
  const float* a2s = (const float*)d_in[7];
  const float* a2d = (const float*)d_in[8];
  const float* b2  = (const float*)d_in[9];
  const int E0 = in_sizes[1] / 2;
  const int* esrc = eidx;
  const int* edst = eidx + E0;
  const int E = E0 + NN;

  char* w = (char*)d_ws;
  auto carve = [&](size_t bytes) {
    void* p = (void*)w;
    w += (bytes + 255) & ~(size_t)255;
    return p;
  };
  int* deg      = (int*)carve((size_t)NN * 4);
  int* offs     = (int*)carve((size_t)(NN + 1) * 4);
  int* cursor   = (int*)carve((size_t)NN * 4);
  int* nbr      = (int*)carve((size_t)E * 4);
  float* es1    = (float*)carve((size_t)NN * NHEADS * 4);
  float* ed1    = (float*)carve((size_t)NN * NHEADS * 4);
  unsigned short* W1t   = (unsigned short*)carve((size_t)NF * NHID * 2);
  unsigned short* W2t   = (unsigned short*)carve((size_t)NHID * NHEADS * NCLASS * 2);
  unsigned short* h1b   = (unsigned short*)carve((size_t)NN * NHID * 2);
  unsigned short* out1b = (unsigned short*)carve((size_t)NN * NHID * 2);
  unsigned short* h2b   = (unsigned short*)carve((size_t)NN * NHEADS * NCLASS * 2);

  // CSR build
  k_init_deg<<<(NN + 255) / 256, 256, 0, stream>>>(deg);
  k_count<<<(E0 + 255) / 256, 256, 0, stream>>>(edst, E0, deg);
  k_scan<<<1, 1024, 0, stream>>>(deg, offs, cursor);
  k_scatter<<<(E0 + NN + 255) / 256, 256, 0, stream>>>(esrc, edst, E0, cursor, nbr);

  // weight casts
  k_castWt<<<(NF * NHID + 255) / 256, 256, 0, stream>>>(W1, W1t, NF, NHID);
  k_castWt_perm<<<(NHID * NHEADS * NCLASS + 255) / 256, 256, 0, stream>>>(W2, W2t, NHID);

  // layer 1 (A-cast fused into GEMM)
  k_gemm_f32a<<<dim3((NN + 63) / 64, NHID / 256), 256, 0, stream>>>(x, W1t, h1b,
                                                                    NN, NF, NHID);
  k_escore_c<32><<<(NN * NHEADS + 255) / 256, 256, 0, stream>>>(h1b, a1s, a1d, es1, ed1);
  k_agg1f<<<(NN + 3) / 4, 256, 0, stream>>>(offs, nbr, h1b, es1, ed1, b1, out1b);

  // layer 2
  k_gemm_bf<<<dim3((NN + 63) / 64, (NHEADS * NCLASS) / 256), 256, 0, stream>>>(
      out1b, W2t, h2b, NN, NHID, NHEADS * NCLASS);
  k_escore_p2<<<(NN + 3) / 4, 256, 0, stream>>>(h2b, a2s, a2d, es1, ed1);
  k_agg2f<<<(NN + 3) / 4, 256, 0, stream>>>(offs, nbr, h2b, es1, ed1, b2, (float*)d_out);
}

// Round 6
// 570.959 us; speedup vs baseline: 1.1196x; 1.1196x over previous
//
#include <hip/hip_runtime.h>
#include <math.h>

#define NN 50000
#define NF 512
#define NHID 256
#define NCLASS 64
#define NHEADS 8

typedef __attribute__((ext_vector_type(8))) short bf16x8;
typedef __attribute__((ext_vector_type(4))) float f32x4;
typedef __attribute__((ext_vector_type(2))) float f32x2;
typedef __attribute__((ext_vector_type(4))) unsigned int u32x4;
typedef __attribute__((ext_vector_type(2))) unsigned int u32x2;

static __device__ __forceinline__ unsigned short f2bf(float f) {
  unsigned int u = __float_as_uint(f);
  unsigned int r = (u + 0x7fffu + ((u >> 16) & 1u)) >> 16;
  return (unsigned short)r;
}
static __device__ __forceinline__ float bf2f(unsigned short u) {
  return __uint_as_float(((unsigned int)u) << 16);
}
static __device__ __forceinline__ float2 bfpair(unsigned int u) {
  return make_float2(__uint_as_float(u << 16), __uint_as_float(u & 0xffff0000u));
}

// ---- inline-asm gathers: compiler tracks zero vmem in hot loops ----
static __device__ __forceinline__ u32x4 gld128(const void* p) {
  u32x4 r;
  asm volatile("global_load_dwordx4 %0, %1, off"
               : "=v"(r) : "v"((unsigned long long)p));
  return r;
}
static __device__ __forceinline__ u32x2 gld64(const void* p) {
  u32x2 r;
  asm volatile("global_load_dwordx2 %0, %1, off"
               : "=v"(r) : "v"((unsigned long long)p));
  return r;
}
static __device__ __forceinline__ int gld32i(const void* p) {
  int r;
  asm volatile("global_load_dword %0, %1, off"
               : "=v"(r) : "v"((unsigned long long)p));
  return r;
}
static __device__ __forceinline__ float gld32f(const void* p) {
  float r;
  asm volatile("global_load_dword %0, %1, off"
               : "=v"(r) : "v"((unsigned long long)p));
  return r;
}
#define VMCNT0()                                        \
  do {                                                  \
    asm volatile("s_waitcnt vmcnt(0)" ::: "memory");    \
    __builtin_amdgcn_sched_barrier(0);                  \
  } while (0)

// ---------------- CSR build ----------------
__global__ void k_init_deg(int* deg) {
  int i = blockIdx.x * blockDim.x + threadIdx.x;
  if (i < NN) deg[i] = 1;  // self loop
}

__global__ void k_count(const int* __restrict__ dst, int E0, int* deg) {
  int i = blockIdx.x * blockDim.x + threadIdx.x;
  if (i < E0) atomicAdd(&deg[dst[i]], 1);
}

__global__ __launch_bounds__(1024) void k_scan(const int* __restrict__ deg, int* offs,
                                               int* cursor) {
  __shared__ int wbase[16];
  __shared__ int srun;
  int tid = threadIdx.x;
  int lane = tid & 63;
  int wv = tid >> 6;
  if (tid == 0) srun = 0;
  __syncthreads();
  for (int base = 0; base < NN; base += 4096) {
    int i = base + tid * 4;
    int4 v;
    if (i + 3 < NN) {
      v = *(const int4*)(deg + i);
    } else {
      v.x = (i + 0 < NN) ? deg[i + 0] : 0;
      v.y = (i + 1 < NN) ? deg[i + 1] : 0;
      v.z = (i + 2 < NN) ? deg[i + 2] : 0;
      v.w = (i + 3 < NN) ? deg[i + 3] : 0;
    }
    int tot = v.x + v.y + v.z + v.w;
    int s = tot;
    #pragma unroll
    for (int o = 1; o < 64; o <<= 1) {
      int t = __shfl_up(s, o);
      if (lane >= o) s += t;
    }
    if (lane == 63) wbase[wv] = s;
    __syncthreads();
    if (tid == 0) {
      int run = srun;
      #pragma unroll
      for (int w2 = 0; w2 < 16; w2++) {
        int t = wbase[w2];
        wbase[w2] = run;
        run += t;
      }
      srun = run;
    }
    __syncthreads();
    int p = wbase[wv] + s - tot;
    if (i + 0 < NN) { offs[i + 0] = p; cursor[i + 0] = p; p += v.x; }
    if (i + 1 < NN) { offs[i + 1] = p; cursor[i + 1] = p; p += v.y; }
    if (i + 2 < NN) { offs[i + 2] = p; cursor[i + 2] = p; p += v.z; }
    if (i + 3 < NN) { offs[i + 3] = p; cursor[i + 3] = p; }
  }
  __syncthreads();
  if (tid == 0) offs[NN] = srun;
}

__global__ void k_scatter(const int* __restrict__ src, const int* __restrict__ dst,
                          int E0, int* cursor, int* __restrict__ nbr) {
  int i = blockIdx.x * blockDim.x + threadIdx.x;
  if (i < E0) {
    int pos = atomicAdd(&cursor[dst[i]], 1);
    nbr[pos] = src[i];
  } else if (i < E0 + NN) {
    int v = i - E0;
    int pos = atomicAdd(&cursor[v], 1);
    nbr[pos] = v;
  }
}

// ---------------- casts ----------------
__global__ void k_cast4(const float* __restrict__ in, unsigned short* __restrict__ out,
                        int n4) {
  int i = blockIdx.x * blockDim.x + threadIdx.x;
  if (i >= n4) return;
  float4 v = *(const float4*)(in + (size_t)i * 4);
  ushort4 o;
  o.x = f2bf(v.x); o.y = f2bf(v.y); o.z = f2bf(v.z); o.w = f2bf(v.w);
  *(ushort4*)(out + (size_t)i * 4) = o;
}

__global__ void k_castWt(const float* __restrict__ W, unsigned short* __restrict__ Wt,
                         int K, int cols) {
  int i = blockIdx.x * blockDim.x + threadIdx.x;
  if (i >= K * cols) return;
  int k = i / cols, c = i % cols;
  Wt[(size_t)c * K + k] = f2bf(W[i]);
}

__global__ void k_castWt_perm(const float* __restrict__ W, unsigned short* __restrict__ Wt,
                              int K) {
  int i = blockIdx.x * blockDim.x + threadIdx.x;
  if (i >= K * NHEADS * NCLASS) return;
  int k = i / (NHEADS * NCLASS);
  int rem = i % (NHEADS * NCLASS);
  int h = rem / NCLASS, c = rem % NCLASS;
  Wt[(size_t)(c * NHEADS + h) * K + k] = f2bf(W[i]);
}

// bf16 h2 -> fp8 e4m3 copy (gather payload for agg2f). 8 values / thread.
__global__ void k_cast_fp8(const unsigned short* __restrict__ in,
                           unsigned char* __restrict__ out, int n8) {
  int i = blockIdx.x * blockDim.x + threadIdx.x;
  if (i >= n8) return;
  uint4 raw = *(const uint4*)(in + (size_t)i * 8);
  float2 p0 = bfpair(raw.x), p1 = bfpair(raw.y), p2 = bfpair(raw.z), p3 = bfpair(raw.w);
  int lo = 0, hi = 0;
  lo = __builtin_amdgcn_cvt_pk_fp8_f32(p0.x, p0.y, lo, false);
  lo = __builtin_amdgcn_cvt_pk_fp8_f32(p1.x, p1.y, lo, true);
  hi = __builtin_amdgcn_cvt_pk_fp8_f32(p2.x, p2.y, hi, false);
  hi = __builtin_amdgcn_cvt_pk_fp8_f32(p3.x, p3.y, hi, true);
  u32x2 o; o[0] = (unsigned int)lo; o[1] = (unsigned int)hi;
  *(u32x2*)(out + (size_t)i * 8) = o;
}

// ---------------- bf16 MFMA GEMM, LDS-staged B, bf16 output ----------------
__global__ __launch_bounds__(256) void k_gemm_bf(const unsigned short* __restrict__ A,
                                                 const unsigned short* __restrict__ Bt,
                                                 unsigned short* __restrict__ C,
                                                 int rows, int K, int cols) {
  __shared__ unsigned short Bs[256 * 40];  // 20 KB
  int t = threadIdx.x;
  int wave = t >> 6, lane = t & 63;
  int quad = lane >> 4, sixt = lane & 15;
  int rb = blockIdx.x * 64 + (wave >> 1) * 32;
  int cw = (wave & 1) * 128;
  int cbw = blockIdx.y * 256 + cw;
  int r0 = rb + sixt, r1 = rb + 16 + sixt;
  const unsigned short* Ap0 = A + (size_t)(r0 < rows ? r0 : 0) * K + quad * 8;
  const unsigned short* Ap1 = A + (size_t)(r1 < rows ? r1 : 0) * K + quad * 8;
  const unsigned short* Bg = Bt + (size_t)(blockIdx.y * 256 + (t >> 2)) * K + (t & 3) * 8;
  const size_t BgStep = (size_t)64 * K;
  char* BsW = (char*)Bs + (t >> 2) * 80 + (t & 3) * 16;
  f32x4 acc0[8] = {}, acc1[8] = {};
  for (int k0 = 0; k0 < K; k0 += 32) {
    uint4 v0 = *(const uint4*)(Bg + k0);
    uint4 v1 = *(const uint4*)(Bg + BgStep + k0);
    uint4 v2 = *(const uint4*)(Bg + 2 * BgStep + k0);
    uint4 v3 = *(const uint4*)(Bg + 3 * BgStep + k0);
    bf16x8 a0 = *(const bf16x8*)(Ap0 + k0);
    bf16x8 a1 = *(const bf16x8*)(Ap1 + k0);
    *(uint4*)(BsW) = v0;
    *(uint4*)(BsW + 64 * 80) = v1;
    *(uint4*)(BsW + 128 * 80) = v2;
    *(uint4*)(BsW + 192 * 80) = v3;
    __syncthreads();
    #pragma unroll
    for (int g = 0; g < 8; g++) {
      bf16x8 b = *(const bf16x8*)((const char*)Bs + (cw + g * 16 + sixt) * 80 + quad * 16);
      acc0[g] = __builtin_amdgcn_mfma_f32_16x16x32_bf16(a0, b, acc0[g], 0, 0, 0);
      acc1[g] = __builtin_amdgcn_mfma_f32_16x16x32_bf16(a1, b, acc1[g], 0, 0, 0);
    }
    __syncthreads();
  }
  #pragma unroll
  for (int r = 0; r < 4; r++) {
    int row = rb + quad * 4 + r;
    if (row < rows) {
      unsigned short* out = C + (size_t)row * cols + cbw + sixt;
      #pragma unroll
      for (int g = 0; g < 8; g++) out[g * 16] = f2bf(acc0[g][r]);
    }
    int row2 = row + 16;
    if (row2 < rows) {
      unsigned short* out = C + (size_t)row2 * cols + cbw + sixt;
      #pragma unroll
      for (int g = 0; g < 8; g++) out[g * 16] = f2bf(acc1[g][r]);
    }
  }
}

// ---------------- edge-score dots, contiguous layout (layer 1) ----------------
template <int C>
__global__ void k_escore_c(const unsigned short* __restrict__ h,
                           const float* __restrict__ asr, const float* __restrict__ ads,
                           float* __restrict__ es, float* __restrict__ ed) {
  int idx = blockIdx.x * blockDim.x + threadIdx.x;  // n*8 + head
  if (idx >= NN * NHEADS) return;
  int hd = idx & 7;
  const unsigned short* row = h + (size_t)idx * C;
  float s = 0.f, d = 0.f;
  #pragma unroll
  for (int c8 = 0; c8 < C / 8; c8++) {
    uint4 raw = *(const uint4*)(row + c8 * 8);
    float2 p0 = bfpair(raw.x), p1 = bfpair(raw.y), p2 = bfpair(raw.z), p3 = bfpair(raw.w);
    const float* as_ = asr + hd * C + c8 * 8;
    const float* ad_ = ads + hd * C + c8 * 8;
    s += p0.x * as_[0] + p0.y * as_[1] + p1.x * as_[2] + p1.y * as_[3] +
         p2.x * as_[4] + p2.y * as_[5] + p3.x * as_[6] + p3.y * as_[7];
    d += p0.x * ad_[0] + p0.y * ad_[1] + p1.x * ad_[2] + p1.y * ad_[3] +
         p2.x * ad_[4] + p2.y * ad_[5] + p3.x * ad_[6] + p3.y * ad_[7];
  }
  es[idx] = s;
  ed[idx] = d;
}

// ---------------- edge-score dots, permuted layout (layer 2) ----------------
__global__ void k_escore_p(const unsigned short* __restrict__ h,
                           const float* __restrict__ asr, const float* __restrict__ ads,
                           float* __restrict__ es, float* __restrict__ ed) {
  int idx = blockIdx.x * blockDim.x + threadIdx.x;  // n*8 + head
  if (idx >= NN * NHEADS) return;
  int hd = idx & 7;
  int n = idx >> 3;
  const unsigned short* row = h + (size_t)n * (NHEADS * NCLASS) + hd;
  float s = 0.f, d = 0.f;
  #pragma unroll
  for (int c = 0; c < NCLASS; c++) {
    float v = bf2f(row[c * NHEADS]);
    s += v * asr[hd * NCLASS + c];
    d += v * ads[hd * NCLASS + c];
  }
  es[idx] = s;
  ed[idx] = d;
}

// ---------------- fused single-pass online-softmax + layer-1 aggregation ----------
// (round-3 validated structure)
__global__ __launch_bounds__(256) void k_agg1f(const int* __restrict__ offs,
                                               const int* __restrict__ nbr,
                                               const unsigned short* __restrict__ h1,
                                               const float* __restrict__ es,
                                               const float* __restrict__ ed,
                                               const float* __restrict__ b1,
                                               unsigned short* __restrict__ out) {
  int node = blockIdx.x * 4 + (threadIdx.x >> 6);
  if (node >= NN) return;
  int lane = threadIdx.x & 63;
  int h = lane & 7;
  int sub = lane >> 3;  // coef-phase edge slot; ALSO consume-phase head
  int col = lane << 2;  // consume-phase 4 channels
  int beg = offs[node], end = offs[node + 1];
  float edst = ed[node * NHEADS + h];
  int kb = beg;
  int iA = kb + (lane & 7); if (iA > end - 1) iA = end - 1;
  int vt = gld32i(nbr + iA);
  int vtN = 0;
  if (kb + 8 < end) {
    int iB = kb + 8 + (lane & 7); if (iB > end - 1) iB = end - 1;
    vtN = gld32i(nbr + iB);
  }
  VMCNT0();
  int se[8];
  #pragma unroll
  for (int e = 0; e < 8; e++) se[e] = __shfl(vt, e);
  float esv;
  {
    int sv = __shfl(vt, sub);
    esv = gld32f(es + (size_t)sv * NHEADS + h);
  }
  VMCNT0();
  float m = -1e30f, z = 0.f;
  float4 acc = make_float4(0.f, 0.f, 0.f, 0.f);
  while (true) {
    int cnt = end - kb; if (cnt > 8) cnt = 8;
    u32x2 r[8];
    #pragma unroll
    for (int e = 0; e < 8; e++)
      if (e < cnt) r[e] = gld64(h1 + (size_t)se[e] * NHID + col);
    bool more = kb + 8 < end, more2 = kb + 16 < end;
    int vt2 = 0;
    if (more2) {
      int iC = kb + 16 + (lane & 7); if (iC > end - 1) iC = end - 1;
      vt2 = gld32i(nbr + iC);
    }
    float esvN = 0.f;
    if (more) {
      int svN = __shfl(vtN, sub);
      esvN = gld32f(es + (size_t)svN * NHEADS + h);
    }
    // coef phase (overlaps in-flight gathers)
    float ar = esv + edst;
    ar = (ar > 0.f) ? ar : 0.2f * ar;
    float a = (kb + sub < end) ? ar : -1e30f;
    float gm = a;
    #pragma unroll
    for (int o = 8; o < 64; o <<= 1) gm = fmaxf(gm, __shfl_xor(gm, o));
    float mn = fmaxf(m, gm);
    float ee = __expf(a - mn);
    float zg = ee;
    #pragma unroll
    for (int o = 8; o < 64; o <<= 1) zg += __shfl_xor(zg, o);
    float sc = __expf(m - mn);
    z = z * sc + zg;
    m = mn;
    VMCNT0();
    // rescale + consume
    float sch = __shfl(sc, sub);
    acc.x *= sch; acc.y *= sch; acc.z *= sch; acc.w *= sch;
    #pragma unroll
    for (int e = 0; e < 8; e++) {
      if (e < cnt) {
        float ce = __shfl(ee, e * 8 + sub);  // lane 8e+head: edge e, head==sub
        float2 p0 = bfpair(r[e][0]), p1 = bfpair(r[e][1]);
        acc.x += ce * p0.x;
        acc.y += ce * p0.y;
        acc.z += ce * p1.x;
        acc.w += ce * p1.y;
      }
    }
    if (!more) break;
    kb += 8;
    #pragma unroll
    for (int e = 0; e < 8; e++) se[e] = __shfl(vtN, e);
    esv = esvN;
    vtN = vt2;
  }
  float inv = 1.f / z;
  float ivh = __shfl(inv, sub);
  ushort4 o;
  o.x = f2bf(fmaxf(acc.x * ivh + b1[col + 0], 0.f));
  o.y = f2bf(fmaxf(acc.y * ivh + b1[col + 1], 0.f));
  o.z = f2bf(fmaxf(acc.z * ivh + b1[col + 2], 0.f));
  o.w = f2bf(fmaxf(acc.w * ivh + b1[col + 3], 0.f));
  *(ushort4*)(out + (size_t)node * NHID + col) = o;
}

// ---------------- fused single-pass online-softmax + layer-2 agg + mean + lsm ------
// (round-3 structure; gather payload is fp8 e4m3: 512 B rows, 8 B/lane)
__global__ __launch_bounds__(256) void k_agg2f(const int* __restrict__ offs,
                                               const int* __restrict__ nbr,
                                               const unsigned char* __restrict__ h2f8,
                                               const float* __restrict__ es,
                                               const float* __restrict__ ed,
                                               const float* __restrict__ b2,
                                               float* __restrict__ out) {
  __shared__ __align__(16) float cs[4][64];
  int wv = threadIdx.x >> 6;
  int node = blockIdx.x * 4 + wv;
  if (node >= NN) return;
  int lane = threadIdx.x & 63;
  int h = lane & 7;
  int sub = lane >> 3;
  int beg = offs[node], end = offs[node + 1];
  float edst = ed[node * NHEADS + h];
  int kb = beg;
  int iA = kb + (lane & 7); if (iA > end - 1) iA = end - 1;
  int vt = gld32i(nbr + iA);
  int vtN = 0;
  if (kb + 8 < end) {
    int iB = kb + 8 + (lane & 7); if (iB > end - 1) iB = end - 1;
    vtN = gld32i(nbr + iB);
  }
  VMCNT0();
  int se[8];
  #pragma unroll
  for (int e = 0; e < 8; e++) se[e] = __shfl(vt, e);
  float esv;
  {
    int sv = __shfl(vt, sub);
    esv = gld32f(es + (size_t)sv * NHEADS + h);
  }
  VMCNT0();
  float m = -1e30f, z = 0.f;
  float acc[8] = {};
  while (true) {
    int cnt = end - kb; if (cnt > 8) cnt = 8;
    u32x2 r[8];
    #pragma unroll
    for (int e = 0; e < 8; e++)
      if (e < cnt) r[e] = gld64(h2f8 + (size_t)se[e] * (NHEADS * NCLASS) + (lane << 3));
    bool more = kb + 8 < end, more2 = kb + 16 < end;
    int vt2 = 0;
    if (more2) {
      int iC = kb + 16 + (lane & 7); if (iC > end - 1) iC = end - 1;
      vt2 = gld32i(nbr + iC);
    }
    float esvN = 0.f;
    if (more) {
      int svN = __shfl(vtN, sub);
      esvN = gld32f(es + (size_t)svN * NHEADS + h);
    }
    // coef phase (overlaps in-flight gathers)
    float ar = esv + edst;
    ar = (ar > 0.f) ? ar : 0.2f * ar;
    float a = (kb + sub < end) ? ar : -1e30f;
    float gm = a;
    #pragma unroll
    for (int o = 8; o < 64; o <<= 1) gm = fmaxf(gm, __shfl_xor(gm, o));
    float mn = fmaxf(m, gm);
    float ee = __expf(a - mn);
    float zg = ee;
    #pragma unroll
    for (int o = 8; o < 64; o <<= 1) zg += __shfl_xor(zg, o);
    float sc = __expf(m - mn);
    z = z * sc + zg;
    m = mn;
    cs[wv][lane] = ee;  // per-wave staging, no barrier needed
    VMCNT0();
    // rescale + consume (fp8 -> f32 via v_cvt_pk_f32_fp8)
    #pragma unroll
    for (int hh = 0; hh < 8; hh++) acc[hh] *= __shfl(sc, hh);
    #pragma unroll
    for (int e = 0; e < 8; e++) {
      if (e < cnt) {
        float4 cA = *(const float4*)&cs[wv][e * 8];
        float4 cB = *(const float4*)&cs[wv][e * 8 + 4];
        f32x2 q0 = __builtin_amdgcn_cvt_pk_f32_fp8((int)r[e][0], false);
        f32x2 q1 = __builtin_amdgcn_cvt_pk_f32_fp8((int)r[e][0], true);
        f32x2 q2 = __builtin_amdgcn_cvt_pk_f32_fp8((int)r[e][1], false);
        f32x2 q3 = __builtin_amdgcn_cvt_pk_f32_fp8((int)r[e][1], true);
        acc[0] += cA.x * q0.x;
        acc[1] += cA.y * q0.y;
        acc[2] += cA.z * q1.x;
        acc[3] += cA.w * q1.y;
        acc[4] += cB.x * q2.x;
        acc[5] += cB.y * q2.y;
        acc[6] += cB.z * q3.x;
        acc[7] += cB.w * q3.y;
      }
    }
    if (!more) break;
    kb += 8;
    #pragma unroll
    for (int e = 0; e < 8; e++) se[e] = __shfl(vtN, e);
    esv = esvN;
    vtN = vt2;
  }
  float inv = 1.f / z;
  float val = 0.f;
  #pragma unroll
  for (int hh = 0; hh < 8; hh++) val += acc[hh] * __shfl(inv, hh);
  val = val * 0.125f + b2[lane];
  float mx = val;
  #pragma unroll
  for (int o = 32; o > 0; o >>= 1) mx = fmaxf(mx, __shfl_xor(mx, o));
  float ex = __expf(val - mx);
  float sm = ex;
  #pragma unroll
  for (int o = 32; o > 0; o >>= 1) sm += __shfl_xor(sm, o);
  out[(size_t)node * NCLASS + lane] = val - mx - __logf(sm);
}

// ---------------- launch ----------------
extern "C" void kernel_launch(void* const* d_in, const int* in_sizes, int n_in,
                              void* d_out, int out_size, void* d_ws, size_t ws_size,
                              hipStream_t stream) {
  const float* x   = (const float*)d_in[0];
  const int* eidx  = (const int*)d_in[1];
  const float* W1  = (const float*)d_in[2];
  const float* a1s = (const float*)d_in[3];
  const float* a1d = (const float*)d_in[4];
  const float* b1  = (const float*)d_in[5];
  const float* W2  = (const float*)d_in[6];
  const float* a2s = (const float*)d_in[7];
  const float* a2d = (const float*)d_in[8];
  const float* b2  = (const float*)d_in[9];
  const int E0 = in_sizes[1] / 2;
  const int* esrc = eidx;
  const int* edst = eidx + E0;
  const int E = E0 + NN;

  char* w = (char*)d_ws;
  auto carve = [&](size_t bytes) {
    void* p = (void*)w;
    w += (bytes + 255) & ~(size_t)255;
    return p;
  };
  int* deg      = (int*)carve((size_t)NN * 4);
  int* offs     = (int*)carve((size_t)(NN + 1) * 4);
  int* cursor   = (int*)carve((size_t)NN * 4);
  int* nbr      = (int*)carve((size_t)E * 4);
  float* es1    = (float*)carve((size_t)NN * NHEADS * 4);
  float* ed1    = (float*)carve((size_t)NN * NHEADS * 4);
  unsigned short* xbf   = (unsigned short*)carve((size_t)NN * NF * 2);
  unsigned short* W1t   = (unsigned short*)carve((size_t)NF * NHID * 2);
  unsigned short* W2t   = (unsigned short*)carve((size_t)NHID * NHEADS * NCLASS * 2);
  unsigned short* h1b   = (unsigned short*)carve((size_t)NN * NHID * 2);
  unsigned short* out1b = (unsigned short*)carve((size_t)NN * NHID * 2);
  unsigned short* h2b   = (unsigned short*)carve((size_t)NN * NHEADS * NCLASS * 2);
  // fp8 copy of h2 reuses the xbf buffer (xbf dead after GEMM1)
  unsigned char* h2f8 = (unsigned char*)xbf;

  // CSR build
  k_init_deg<<<(NN + 255) / 256, 256, 0, stream>>>(deg);
  k_count<<<(E0 + 255) / 256, 256, 0, stream>>>(edst, E0, deg);
  k_scan<<<1, 1024, 0, stream>>>(deg, offs, cursor);
  k_scatter<<<(E0 + NN + 255) / 256, 256, 0, stream>>>(esrc, edst, E0, cursor, nbr);

  // casts
  k_cast4<<<(NN * NF / 4 + 255) / 256, 256, 0, stream>>>(x, xbf, NN * NF / 4);
  k_castWt<<<(NF * NHID + 255) / 256, 256, 0, stream>>>(W1, W1t, NF, NHID);
  k_castWt_perm<<<(NHID * NHEADS * NCLASS + 255) / 256, 256, 0, stream>>>(W2, W2t, NHID);

  // layer 1
  k_gemm_bf<<<dim3((NN + 63) / 64, NHID / 256), 256, 0, stream>>>(xbf, W1t, h1b,
                                                                  NN, NF, NHID);
  k_escore_c<32><<<(NN * NHEADS + 255) / 256, 256, 0, stream>>>(h1b, a1s, a1d, es1, ed1);
  k_agg1f<<<(NN + 3) / 4, 256, 0, stream>>>(offs, nbr, h1b, es1, ed1, b1, out1b);

  // layer 2
  k_gemm_bf<<<dim3((NN + 63) / 64, (NHEADS * NCLASS) / 256), 256, 0, stream>>>(
      out1b, W2t, h2b, NN, NHID, NHEADS * NCLASS);
  k_escore_p<<<(NN * NHEADS + 255) / 256, 256, 0, stream>>>(h2b, a2s, a2d, es1, ed1);
  k_cast_fp8<<<(NN * NHEADS * NCLASS / 8 + 255) / 256, 256, 0, stream>>>(
      h2b, h2f8, NN * NHEADS * NCLASS / 8);
  k_agg2f<<<(NN + 3) / 4, 256, 0, stream>>>(offs, nbr, h2f8, es1, ed1, b2,
                                            (float*)d_out);
}

// Round 7
// 547.989 us; speedup vs baseline: 1.1665x; 1.0419x over previous
//
#include <hip/hip_runtime.h>
#include <math.h>

#define NN 50000
#define NF 512
#define NHID 256
#define NCLASS 64
#define NHEADS 8

typedef __attribute__((ext_vector_type(8))) short bf16x8;
typedef __attribute__((ext_vector_type(4))) float f32x4;
typedef __attribute__((ext_vector_type(2))) float f32x2;
typedef __attribute__((ext_vector_type(4))) unsigned int u32x4;
typedef __attribute__((ext_vector_type(2))) unsigned int u32x2;

static __device__ __forceinline__ unsigned short f2bf(float f) {
  unsigned int u = __float_as_uint(f);
  unsigned int r = (u + 0x7fffu + ((u >> 16) & 1u)) >> 16;
  return (unsigned short)r;
}
static __device__ __forceinline__ float bf2f(unsigned short u) {
  return __uint_as_float(((unsigned int)u) << 16);
}
static __device__ __forceinline__ float2 bfpair(unsigned int u) {
  return make_float2(__uint_as_float(u << 16), __uint_as_float(u & 0xffff0000u));
}

// ---- inline-asm gathers: compiler tracks zero vmem in hot loops ----
static __device__ __forceinline__ u32x2 gld64(const void* p) {
  u32x2 r;
  asm volatile("global_load_dwordx2 %0, %1, off"
               : "=v"(r) : "v"((unsigned long long)p));
  return r;
}
static __device__ __forceinline__ int gld32i(const void* p) {
  int r;
  asm volatile("global_load_dword %0, %1, off"
               : "=v"(r) : "v"((unsigned long long)p));
  return r;
}
static __device__ __forceinline__ float gld32f(const void* p) {
  float r;
  asm volatile("global_load_dword %0, %1, off"
               : "=v"(r) : "v"((unsigned long long)p));
  return r;
}
#define VMCNT0()                                        \
  do {                                                  \
    asm volatile("s_waitcnt vmcnt(0)" ::: "memory");    \
    __builtin_amdgcn_sched_barrier(0);                  \
  } while (0)

// ---------------- CSR build ----------------
__global__ void k_init_deg(int* deg) {
  int i = blockIdx.x * blockDim.x + threadIdx.x;
  if (i < NN) deg[i] = 1;  // self loop
}

__global__ void k_count(const int* __restrict__ dst, int E0, int* deg) {
  int i = blockIdx.x * blockDim.x + threadIdx.x;
  if (i < E0) atomicAdd(&deg[dst[i]], 1);
}

__global__ __launch_bounds__(1024) void k_scan(const int* __restrict__ deg, int* offs,
                                               int* cursor) {
  __shared__ int wbase[16];
  __shared__ int srun;
  int tid = threadIdx.x;
  int lane = tid & 63;
  int wv = tid >> 6;
  if (tid == 0) srun = 0;
  __syncthreads();
  for (int base = 0; base < NN; base += 4096) {
    int i = base + tid * 4;
    int4 v;
    if (i + 3 < NN) {
      v = *(const int4*)(deg + i);
    } else {
      v.x = (i + 0 < NN) ? deg[i + 0] : 0;
      v.y = (i + 1 < NN) ? deg[i + 1] : 0;
      v.z = (i + 2 < NN) ? deg[i + 2] : 0;
      v.w = (i + 3 < NN) ? deg[i + 3] : 0;
    }
    int tot = v.x + v.y + v.z + v.w;
    int s = tot;
    #pragma unroll
    for (int o = 1; o < 64; o <<= 1) {
      int t = __shfl_up(s, o);
      if (lane >= o) s += t;
    }
    if (lane == 63) wbase[wv] = s;
    __syncthreads();
    if (tid == 0) {
      int run = srun;
      #pragma unroll
      for (int w2 = 0; w2 < 16; w2++) {
        int t = wbase[w2];
        wbase[w2] = run;
        run += t;
      }
      srun = run;
    }
    __syncthreads();
    int p = wbase[wv] + s - tot;
    if (i + 0 < NN) { offs[i + 0] = p; cursor[i + 0] = p; p += v.x; }
    if (i + 1 < NN) { offs[i + 1] = p; cursor[i + 1] = p; p += v.y; }
    if (i + 2 < NN) { offs[i + 2] = p; cursor[i + 2] = p; p += v.z; }
    if (i + 3 < NN) { offs[i + 3] = p; cursor[i + 3] = p; }
  }
  __syncthreads();
  if (tid == 0) offs[NN] = srun;
}

__global__ void k_scatter(const int* __restrict__ src, const int* __restrict__ dst,
                          int E0, int* cursor, int* __restrict__ nbr) {
  int i = blockIdx.x * blockDim.x + threadIdx.x;
  if (i < E0) {
    int pos = atomicAdd(&cursor[dst[i]], 1);
    nbr[pos] = src[i];
  } else if (i < E0 + NN) {
    int v = i - E0;
    int pos = atomicAdd(&cursor[v], 1);
    nbr[pos] = v;
  }
}

// ---------------- casts ----------------
__global__ void k_cast4(const float* __restrict__ in, unsigned short* __restrict__ out,
                        int n4) {
  int i = blockIdx.x * blockDim.x + threadIdx.x;
  if (i >= n4) return;
  float4 v = *(const float4*)(in + (size_t)i * 4);
  ushort4 o;
  o.x = f2bf(v.x); o.y = f2bf(v.y); o.z = f2bf(v.z); o.w = f2bf(v.w);
  *(ushort4*)(out + (size_t)i * 4) = o;
}

__global__ void k_castWt(const float* __restrict__ W, unsigned short* __restrict__ Wt,
                         int K, int cols) {
  int i = blockIdx.x * blockDim.x + threadIdx.x;
  if (i >= K * cols) return;
  int k = i / cols, c = i % cols;
  Wt[(size_t)c * K + k] = f2bf(W[i]);
}

__global__ void k_castWt_perm(const float* __restrict__ W, unsigned short* __restrict__ Wt,
                              int K) {
  int i = blockIdx.x * blockDim.x + threadIdx.x;
  if (i >= K * NHEADS * NCLASS) return;
  int k = i / (NHEADS * NCLASS);
  int rem = i % (NHEADS * NCLASS);
  int h = rem / NCLASS, c = rem % NCLASS;
  Wt[(size_t)(c * NHEADS + h) * K + k] = f2bf(W[i]);
}

// bf16 -> fp8 e4m3 copy (gather payload). 8 values / thread.
__global__ void k_cast_fp8(const unsigned short* __restrict__ in,
                           unsigned char* __restrict__ out, int n8) {
  int i = blockIdx.x * blockDim.x + threadIdx.x;
  if (i >= n8) return;
  uint4 raw = *(const uint4*)(in + (size_t)i * 8);
  float2 p0 = bfpair(raw.x), p1 = bfpair(raw.y), p2 = bfpair(raw.z), p3 = bfpair(raw.w);
  int lo = 0, hi = 0;
  lo = __builtin_amdgcn_cvt_pk_fp8_f32(p0.x, p0.y, lo, false);
  lo = __builtin_amdgcn_cvt_pk_fp8_f32(p1.x, p1.y, lo, true);
  hi = __builtin_amdgcn_cvt_pk_fp8_f32(p2.x, p2.y, hi, false);
  hi = __builtin_amdgcn_cvt_pk_fp8_f32(p3.x, p3.y, hi, true);
  u32x2 o; o[0] = (unsigned int)lo; o[1] = (unsigned int)hi;
  *(u32x2*)(out + (size_t)i * 8) = o;
}

// ---------------- bf16 MFMA GEMM, LDS-staged B, bf16 output ----------------
__global__ __launch_bounds__(256) void k_gemm_bf(const unsigned short* __restrict__ A,
                                                 const unsigned short* __restrict__ Bt,
                                                 unsigned short* __restrict__ C,
                                                 int rows, int K, int cols) {
  __shared__ unsigned short Bs[256 * 40];  // 20 KB
  int t = threadIdx.x;
  int wave = t >> 6, lane = t & 63;
  int quad = lane >> 4, sixt = lane & 15;
  int rb = blockIdx.x * 64 + (wave >> 1) * 32;
  int cw = (wave & 1) * 128;
  int cbw = blockIdx.y * 256 + cw;
  int r0 = rb + sixt, r1 = rb + 16 + sixt;
  const unsigned short* Ap0 = A + (size_t)(r0 < rows ? r0 : 0) * K + quad * 8;
  const unsigned short* Ap1 = A + (size_t)(r1 < rows ? r1 : 0) * K + quad * 8;
  const unsigned short* Bg = Bt + (size_t)(blockIdx.y * 256 + (t >> 2)) * K + (t & 3) * 8;
  const size_t BgStep = (size_t)64 * K;
  char* BsW = (char*)Bs + (t >> 2) * 80 + (t & 3) * 16;
  f32x4 acc0[8] = {}, acc1[8] = {};
  for (int k0 = 0; k0 < K; k0 += 32) {
    uint4 v0 = *(const uint4*)(Bg + k0);
    uint4 v1 = *(const uint4*)(Bg + BgStep + k0);
    uint4 v2 = *(const uint4*)(Bg + 2 * BgStep + k0);
    uint4 v3 = *(const uint4*)(Bg + 3 * BgStep + k0);
    bf16x8 a0 = *(const bf16x8*)(Ap0 + k0);
    bf16x8 a1 = *(const bf16x8*)(Ap1 + k0);
    *(uint4*)(BsW) = v0;
    *(uint4*)(BsW + 64 * 80) = v1;
    *(uint4*)(BsW + 128 * 80) = v2;
    *(uint4*)(BsW + 192 * 80) = v3;
    __syncthreads();
    #pragma unroll
    for (int g = 0; g < 8; g++) {
      bf16x8 b = *(const bf16x8*)((const char*)Bs + (cw + g * 16 + sixt) * 80 + quad * 16);
      acc0[g] = __builtin_amdgcn_mfma_f32_16x16x32_bf16(a0, b, acc0[g], 0, 0, 0);
      acc1[g] = __builtin_amdgcn_mfma_f32_16x16x32_bf16(a1, b, acc1[g], 0, 0, 0);
    }
    __syncthreads();
  }
  #pragma unroll
  for (int r = 0; r < 4; r++) {
    int row = rb + quad * 4 + r;
    if (row < rows) {
      unsigned short* out = C + (size_t)row * cols + cbw + sixt;
      #pragma unroll
      for (int g = 0; g < 8; g++) out[g * 16] = f2bf(acc0[g][r]);
    }
    int row2 = row + 16;
    if (row2 < rows) {
      unsigned short* out = C + (size_t)row2 * cols + cbw + sixt;
      #pragma unroll
      for (int g = 0; g < 8; g++) out[g * 16] = f2bf(acc1[g][r]);
    }
  }
}

// ---------------- same GEMM, fp8 e4m3 output (layer 2: h2 consumed as fp8) ------
__global__ __launch_bounds__(256) void k_gemm_bf8(const unsigned short* __restrict__ A,
                                                  const unsigned short* __restrict__ Bt,
                                                  unsigned char* __restrict__ C,
                                                  int rows, int K, int cols) {
  __shared__ unsigned short Bs[256 * 40];  // 20 KB
  int t = threadIdx.x;
  int wave = t >> 6, lane = t & 63;
  int quad = lane >> 4, sixt = lane & 15;
  int rb = blockIdx.x * 64 + (wave >> 1) * 32;
  int cw = (wave & 1) * 128;
  int cbw = blockIdx.y * 256 + cw;
  int r0 = rb + sixt, r1 = rb + 16 + sixt;
  const unsigned short* Ap0 = A + (size_t)(r0 < rows ? r0 : 0) * K + quad * 8;
  const unsigned short* Ap1 = A + (size_t)(r1 < rows ? r1 : 0) * K + quad * 8;
  const unsigned short* Bg = Bt + (size_t)(blockIdx.y * 256 + (t >> 2)) * K + (t & 3) * 8;
  const size_t BgStep = (size_t)64 * K;
  char* BsW = (char*)Bs + (t >> 2) * 80 + (t & 3) * 16;
  f32x4 acc0[8] = {}, acc1[8] = {};
  for (int k0 = 0; k0 < K; k0 += 32) {
    uint4 v0 = *(const uint4*)(Bg + k0);
    uint4 v1 = *(const uint4*)(Bg + BgStep + k0);
    uint4 v2 = *(const uint4*)(Bg + 2 * BgStep + k0);
    uint4 v3 = *(const uint4*)(Bg + 3 * BgStep + k0);
    bf16x8 a0 = *(const bf16x8*)(Ap0 + k0);
    bf16x8 a1 = *(const bf16x8*)(Ap1 + k0);
    *(uint4*)(BsW) = v0;
    *(uint4*)(BsW + 64 * 80) = v1;
    *(uint4*)(BsW + 128 * 80) = v2;
    *(uint4*)(BsW + 192 * 80) = v3;
    __syncthreads();
    #pragma unroll
    for (int g = 0; g < 8; g++) {
      bf16x8 b = *(const bf16x8*)((const char*)Bs + (cw + g * 16 + sixt) * 80 + quad * 16);
      acc0[g] = __builtin_amdgcn_mfma_f32_16x16x32_bf16(a0, b, acc0[g], 0, 0, 0);
      acc1[g] = __builtin_amdgcn_mfma_f32_16x16x32_bf16(a1, b, acc1[g], 0, 0, 0);
    }
    __syncthreads();
  }
  #pragma unroll
  for (int r = 0; r < 4; r++) {
    int row = rb + quad * 4 + r;
    if (row < rows) {
      unsigned char* out = C + (size_t)row * cols + cbw + sixt;
      #pragma unroll
      for (int g = 0; g < 8; g++) {
        int wq = __builtin_amdgcn_cvt_pk_fp8_f32(acc0[g][r], acc0[g][r], 0, false);
        out[g * 16] = (unsigned char)(wq & 0xff);
      }
    }
    int row2 = row + 16;
    if (row2 < rows) {
      unsigned char* out = C + (size_t)row2 * cols + cbw + sixt;
      #pragma unroll
      for (int g = 0; g < 8; g++) {
        int wq = __builtin_amdgcn_cvt_pk_fp8_f32(acc1[g][r], acc1[g][r], 0, false);
        out[g * 16] = (unsigned char)(wq & 0xff);
      }
    }
  }
}

// ---------------- edge-score dots, contiguous layout (layer 1) ----------------
template <int C>
__global__ void k_escore_c(const unsigned short* __restrict__ h,
                           const float* __restrict__ asr, const float* __restrict__ ads,
                           float* __restrict__ es, float* __restrict__ ed) {
  int idx = blockIdx.x * blockDim.x + threadIdx.x;  // n*8 + head
  if (idx >= NN * NHEADS) return;
  int hd = idx & 7;
  const unsigned short* row = h + (size_t)idx * C;
  float s = 0.f, d = 0.f;
  #pragma unroll
  for (int c8 = 0; c8 < C / 8; c8++) {
    uint4 raw = *(const uint4*)(row + c8 * 8);
    float2 p0 = bfpair(raw.x), p1 = bfpair(raw.y), p2 = bfpair(raw.z), p3 = bfpair(raw.w);
    const float* as_ = asr + hd * C + c8 * 8;
    const float* ad_ = ads + hd * C + c8 * 8;
    s += p0.x * as_[0] + p0.y * as_[1] + p1.x * as_[2] + p1.y * as_[3] +
         p2.x * as_[4] + p2.y * as_[5] + p3.x * as_[6] + p3.y * as_[7];
    d += p0.x * ad_[0] + p0.y * ad_[1] + p1.x * ad_[2] + p1.y * ad_[3] +
         p2.x * ad_[4] + p2.y * ad_[5] + p3.x * ad_[6] + p3.y * ad_[7];
  }
  es[idx] = s;
  ed[idx] = d;
}

// ---------------- edge-score dots, permuted fp8 layout (layer 2) ----------------
__global__ void k_escore_p8(const unsigned char* __restrict__ h,
                            const float* __restrict__ asr, const float* __restrict__ ads,
                            float* __restrict__ es, float* __restrict__ ed) {
  int idx = blockIdx.x * blockDim.x + threadIdx.x;  // n*8 + head
  if (idx >= NN * NHEADS) return;
  int hd = idx & 7;
  int n = idx >> 3;
  // row layout: byte index = c*8 + h. read the aligned ushort containing (h&~1, h|1).
  const unsigned short* rp =
      (const unsigned short*)(h + (size_t)n * (NHEADS * NCLASS) + (hd & ~1));
  int hi = hd & 1;
  float s = 0.f, d = 0.f;
  #pragma unroll
  for (int c = 0; c < NCLASS; c++) {
    unsigned short w = rp[c * 4];
    f32x2 q = __builtin_amdgcn_cvt_pk_f32_fp8((int)w, false);
    float v = hi ? q.y : q.x;
    s += v * asr[hd * NCLASS + c];
    d += v * ads[hd * NCLASS + c];
  }
  es[idx] = s;
  ed[idx] = d;
}

// ---------------- fused single-pass online-softmax + layer-1 aggregation ----------
// (round-3 structure; gather payload fp8 e4m3: 256 B rows, 4 B/lane)
__global__ __launch_bounds__(256) void k_agg1f(const int* __restrict__ offs,
                                               const int* __restrict__ nbr,
                                               const unsigned char* __restrict__ h1f8,
                                               const float* __restrict__ es,
                                               const float* __restrict__ ed,
                                               const float* __restrict__ b1,
                                               unsigned short* __restrict__ out) {
  int node = blockIdx.x * 4 + (threadIdx.x >> 6);
  if (node >= NN) return;
  int lane = threadIdx.x & 63;
  int h = lane & 7;
  int sub = lane >> 3;  // coef-phase edge slot; ALSO consume-phase head
  int col = lane << 2;  // consume-phase 4 channels
  int beg = offs[node], end = offs[node + 1];
  float edst = ed[node * NHEADS + h];
  int kb = beg;
  int iA = kb + (lane & 7); if (iA > end - 1) iA = end - 1;
  int vt = gld32i(nbr + iA);
  int vtN = 0;
  if (kb + 8 < end) {
    int iB = kb + 8 + (lane & 7); if (iB > end - 1) iB = end - 1;
    vtN = gld32i(nbr + iB);
  }
  VMCNT0();
  int se[8];
  #pragma unroll
  for (int e = 0; e < 8; e++) se[e] = __shfl(vt, e);
  float esv;
  {
    int sv = __shfl(vt, sub);
    esv = gld32f(es + (size_t)sv * NHEADS + h);
  }
  VMCNT0();
  float m = -1e30f, z = 0.f;
  float4 acc = make_float4(0.f, 0.f, 0.f, 0.f);
  while (true) {
    int cnt = end - kb; if (cnt > 8) cnt = 8;
    int r[8];
    #pragma unroll
    for (int e = 0; e < 8; e++)
      if (e < cnt) r[e] = gld32i(h1f8 + (size_t)se[e] * NHID + col);
    bool more = kb + 8 < end, more2 = kb + 16 < end;
    int vt2 = 0;
    if (more2) {
      int iC = kb + 16 + (lane & 7); if (iC > end - 1) iC = end - 1;
      vt2 = gld32i(nbr + iC);
    }
    float esvN = 0.f;
    if (more) {
      int svN = __shfl(vtN, sub);
      esvN = gld32f(es + (size_t)svN * NHEADS + h);
    }
    // coef phase (overlaps in-flight gathers)
    float ar = esv + edst;
    ar = (ar > 0.f) ? ar : 0.2f * ar;
    float a = (kb + sub < end) ? ar : -1e30f;
    float gm = a;
    #pragma unroll
    for (int o = 8; o < 64; o <<= 1) gm = fmaxf(gm, __shfl_xor(gm, o));
    float mn = fmaxf(m, gm);
    float ee = __expf(a - mn);
    float zg = ee;
    #pragma unroll
    for (int o = 8; o < 64; o <<= 1) zg += __shfl_xor(zg, o);
    float sc = __expf(m - mn);
    z = z * sc + zg;
    m = mn;
    VMCNT0();
    // rescale + consume (fp8 decode)
    float sch = __shfl(sc, sub);
    acc.x *= sch; acc.y *= sch; acc.z *= sch; acc.w *= sch;
    #pragma unroll
    for (int e = 0; e < 8; e++) {
      if (e < cnt) {
        float ce = __shfl(ee, e * 8 + sub);  // lane 8e+head: edge e, head==sub
        f32x2 q0 = __builtin_amdgcn_cvt_pk_f32_fp8(r[e], false);
        f32x2 q1 = __builtin_amdgcn_cvt_pk_f32_fp8(r[e], true);
        acc.x += ce * q0.x;
        acc.y += ce * q0.y;
        acc.z += ce * q1.x;
        acc.w += ce * q1.y;
      }
    }
    if (!more) break;
    kb += 8;
    #pragma unroll
    for (int e = 0; e < 8; e++) se[e] = __shfl(vtN, e);
    esv = esvN;
    vtN = vt2;
  }
  float inv = 1.f / z;
  float ivh = __shfl(inv, sub);
  ushort4 o;
  o.x = f2bf(fmaxf(acc.x * ivh + b1[col + 0], 0.f));
  o.y = f2bf(fmaxf(acc.y * ivh + b1[col + 1], 0.f));
  o.z = f2bf(fmaxf(acc.z * ivh + b1[col + 2], 0.f));
  o.w = f2bf(fmaxf(acc.w * ivh + b1[col + 3], 0.f));
  *(ushort4*)(out + (size_t)node * NHID + col) = o;
}

// ---------------- fused single-pass online-softmax + layer-2 agg + mean + lsm ------
// (round-3 structure; gather payload fp8 e4m3: 512 B rows, 8 B/lane)
__global__ __launch_bounds__(256) void k_agg2f(const int* __restrict__ offs,
                                               const int* __restrict__ nbr,
                                               const unsigned char* __restrict__ h2f8,
                                               const float* __restrict__ es,
                                               const float* __restrict__ ed,
                                               const float* __restrict__ b2,
                                               float* __restrict__ out) {
  __shared__ __align__(16) float cs[4][64];
  int wv = threadIdx.x >> 6;
  int node = blockIdx.x * 4 + wv;
  if (node >= NN) return;
  int lane = threadIdx.x & 63;
  int h = lane & 7;
  int sub = lane >> 3;
  int beg = offs[node], end = offs[node + 1];
  float edst = ed[node * NHEADS + h];
  int kb = beg;
  int iA = kb + (lane & 7); if (iA > end - 1) iA = end - 1;
  int vt = gld32i(nbr + iA);
  int vtN = 0;
  if (kb + 8 < end) {
    int iB = kb + 8 + (lane & 7); if (iB > end - 1) iB = end - 1;
    vtN = gld32i(nbr + iB);
  }
  VMCNT0();
  int se[8];
  #pragma unroll
  for (int e = 0; e < 8; e++) se[e] = __shfl(vt, e);
  float esv;
  {
    int sv = __shfl(vt, sub);
    esv = gld32f(es + (size_t)sv * NHEADS + h);
  }
  VMCNT0();
  float m = -1e30f, z = 0.f;
  float acc[8] = {};
  while (true) {
    int cnt = end - kb; if (cnt > 8) cnt = 8;
    u32x2 r[8];
    #pragma unroll
    for (int e = 0; e < 8; e++)
      if (e < cnt) r[e] = gld64(h2f8 + (size_t)se[e] * (NHEADS * NCLASS) + (lane << 3));
    bool more = kb + 8 < end, more2 = kb + 16 < end;
    int vt2 = 0;
    if (more2) {
      int iC = kb + 16 + (lane & 7); if (iC > end - 1) iC = end - 1;
      vt2 = gld32i(nbr + iC);
    }
    float esvN = 0.f;
    if (more) {
      int svN = __shfl(vtN, sub);
      esvN = gld32f(es + (size_t)svN * NHEADS + h);
    }
    // coef phase (overlaps in-flight gathers)
    float ar = esv + edst;
    ar = (ar > 0.f) ? ar : 0.2f * ar;
    float a = (kb + sub < end) ? ar : -1e30f;
    float gm = a;
    #pragma unroll
    for (int o = 8; o < 64; o <<= 1) gm = fmaxf(gm, __shfl_xor(gm, o));
    float mn = fmaxf(m, gm);
    float ee = __expf(a - mn);
    float zg = ee;
    #pragma unroll
    for (int o = 8; o < 64; o <<= 1) zg += __shfl_xor(zg, o);
    float sc = __expf(m - mn);
    z = z * sc + zg;
    m = mn;
    cs[wv][lane] = ee;  // per-wave staging, no barrier needed
    VMCNT0();
    // rescale + consume (fp8 -> f32 via v_cvt_pk_f32_fp8)
    #pragma unroll
    for (int hh = 0; hh < 8; hh++) acc[hh] *= __shfl(sc, hh);
    #pragma unroll
    for (int e = 0; e < 8; e++) {
      if (e < cnt) {
        float4 cA = *(const float4*)&cs[wv][e * 8];
        float4 cB = *(const float4*)&cs[wv][e * 8 + 4];
        f32x2 q0 = __builtin_amdgcn_cvt_pk_f32_fp8((int)r[e][0], false);
        f32x2 q1 = __builtin_amdgcn_cvt_pk_f32_fp8((int)r[e][0], true);
        f32x2 q2 = __builtin_amdgcn_cvt_pk_f32_fp8((int)r[e][1], false);
        f32x2 q3 = __builtin_amdgcn_cvt_pk_f32_fp8((int)r[e][1], true);
        acc[0] += cA.x * q0.x;
        acc[1] += cA.y * q0.y;
        acc[2] += cA.z * q1.x;
        acc[3] += cA.w * q1.y;
        acc[4] += cB.x * q2.x;
        acc[5] += cB.y * q2.y;
        acc[6] += cB.z * q3.x;
        acc[7] += cB.w * q3.y;
      }
    }
    if (!more) break;
    kb += 8;
    #pragma unroll
    for (int e = 0; e < 8; e++) se[e] = __shfl(vtN, e);
    esv = esvN;
    vtN = vt2;
  }
  float inv = 1.f / z;
  float val = 0.f;
  #pragma unroll
  for (int hh = 0; hh < 8; hh++) val += acc[hh] * __shfl(inv, hh);
  val = val * 0.125f + b2[lane];
  float mx = val;
  #pragma unroll
  for (int o = 32; o > 0; o >>= 1) mx = fmaxf(mx, __shfl_xor(mx, o));
  float ex = __expf(val - mx);
  float sm = ex;
  #pragma unroll
  for (int o = 32; o > 0; o >>= 1) sm += __shfl_xor(sm, o);
  out[(size_t)node * NCLASS + lane] = val - mx - __logf(sm);
}

// ---------------- launch ----------------
extern "C" void kernel_launch(void* const* d_in, const int* in_sizes, int n_in,
                              void* d_out, int out_size, void* d_ws, size_t ws_size,
                              hipStream_t stream) {
  const float* x   = (const float*)d_in[0];
  const int* eidx  = (const int*)d_in[1];
  const float* W1  = (const float*)d_in[2];
  const float* a1s = (const float*)d_in[3];
  const float* a1d = (const float*)d_in[4];
  const float* b1  = (const float*)d_in[5];
  const float* W2  = (const float*)d_in[6];
  const float* a2s = (const float*)d_in[7];
  const float* a2d = (const float*)d_in[8];
  const float* b2  = (const float*)d_in[9];
  const int E0 = in_sizes[1] / 2;
  const int* esrc = eidx;
  const int* edst = eidx + E0;
  const int E = E0 + NN;

  char* w = (char*)d_ws;
  auto carve = [&](size_t bytes) {
    void* p = (void*)w;
    w += (bytes + 255) & ~(size_t)255;
    return p;
  };
  int* deg      = (int*)carve((size_t)NN * 4);
  int* offs     = (int*)carve((size_t)(NN + 1) * 4);
  int* cursor   = (int*)carve((size_t)NN * 4);
  int* nbr      = (int*)carve((size_t)E * 4);
  float* es1    = (float*)carve((size_t)NN * NHEADS * 4);
  float* ed1    = (float*)carve((size_t)NN * NHEADS * 4);
  unsigned short* xbf   = (unsigned short*)carve((size_t)NN * NF * 2);
  unsigned short* W1t   = (unsigned short*)carve((size_t)NF * NHID * 2);
  unsigned short* W2t   = (unsigned short*)carve((size_t)NHID * NHEADS * NCLASS * 2);
  unsigned short* h1b   = (unsigned short*)carve((size_t)NN * NHID * 2);
  unsigned short* out1b = (unsigned short*)carve((size_t)NN * NHID * 2);
  unsigned char* h1f8   = (unsigned char*)carve((size_t)NN * NHID);
  // fp8 h2 (written directly by GEMM2) reuses the xbf buffer (dead after GEMM1)
  unsigned char* h2f8 = (unsigned char*)xbf;

  // CSR build
  k_init_deg<<<(NN + 255) / 256, 256, 0, stream>>>(deg);
  k_count<<<(E0 + 255) / 256, 256, 0, stream>>>(edst, E0, deg);
  k_scan<<<1, 1024, 0, stream>>>(deg, offs, cursor);
  k_scatter<<<(E0 + NN + 255) / 256, 256, 0, stream>>>(esrc, edst, E0, cursor, nbr);

  // casts
  k_cast4<<<(NN * NF / 4 + 255) / 256, 256, 0, stream>>>(x, xbf, NN * NF / 4);
  k_castWt<<<(NF * NHID + 255) / 256, 256, 0, stream>>>(W1, W1t, NF, NHID);
  k_castWt_perm<<<(NHID * NHEADS * NCLASS + 255) / 256, 256, 0, stream>>>(W2, W2t, NHID);

  // layer 1
  k_gemm_bf<<<dim3((NN + 63) / 64, NHID / 256), 256, 0, stream>>>(xbf, W1t, h1b,
                                                                  NN, NF, NHID);
  k_escore_c<32><<<(NN * NHEADS + 255) / 256, 256, 0, stream>>>(h1b, a1s, a1d, es1, ed1);
  k_cast_fp8<<<(NN * NHID / 8 + 255) / 256, 256, 0, stream>>>(h1b, h1f8, NN * NHID / 8);
  k_agg1f<<<(NN + 3) / 4, 256, 0, stream>>>(offs, nbr, h1f8, es1, ed1, b1, out1b);

  // layer 2 (GEMM writes fp8 directly; escore reads fp8)
  k_gemm_bf8<<<dim3((NN + 63) / 64, (NHEADS * NCLASS) / 256), 256, 0, stream>>>(
      out1b, W2t, h2f8, NN, NHID, NHEADS * NCLASS);
  k_escore_p8<<<(NN * NHEADS + 255) / 256, 256, 0, stream>>>(h2f8, a2s, a2d, es1, ed1);
  k_agg2f<<<(NN + 3) / 4, 256, 0, stream>>>(offs, nbr, h2f8, es1, ed1, b2,
                                            (float*)d_out);
}

// Round 8
// 540.379 us; speedup vs baseline: 1.1829x; 1.0141x over previous
//
#include <hip/hip_runtime.h>
#include <math.h>

#define NN 50000
#define NF 512
#define NHID 256
#define NCLASS 64
#define NHEADS 8
#define SCAN_NBLK ((NN + 1023) / 1024)

typedef __attribute__((ext_vector_type(8))) short bf16x8;
typedef __attribute__((ext_vector_type(4))) float f32x4;
typedef __attribute__((ext_vector_type(2))) float f32x2;
typedef __attribute__((ext_vector_type(2))) unsigned int u32x2;

static __device__ __forceinline__ unsigned short f2bf(float f) {
  unsigned int u = __float_as_uint(f);
  unsigned int r = (u + 0x7fffu + ((u >> 16) & 1u)) >> 16;
  return (unsigned short)r;
}
static __device__ __forceinline__ float bf2f(unsigned short u) {
  return __uint_as_float(((unsigned int)u) << 16);
}
static __device__ __forceinline__ float2 bfpair(unsigned int u) {
  return make_float2(__uint_as_float(u << 16), __uint_as_float(u & 0xffff0000u));
}

// ---- inline-asm gathers: compiler tracks zero vmem in hot loops ----
static __device__ __forceinline__ u32x2 gld64(const void* p) {
  u32x2 r;
  asm volatile("global_load_dwordx2 %0, %1, off"
               : "=v"(r) : "v"((unsigned long long)p));
  return r;
}
static __device__ __forceinline__ int gld32i(const void* p) {
  int r;
  asm volatile("global_load_dword %0, %1, off"
               : "=v"(r) : "v"((unsigned long long)p));
  return r;
}
static __device__ __forceinline__ float gld32f(const void* p) {
  float r;
  asm volatile("global_load_dword %0, %1, off"
               : "=v"(r) : "v"((unsigned long long)p));
  return r;
}
#define VMCNT0()                                        \
  do {                                                  \
    asm volatile("s_waitcnt vmcnt(0)" ::: "memory");    \
    __builtin_amdgcn_sched_barrier(0);                  \
  } while (0)

// ---------------- CSR build ----------------
__global__ void k_init_deg(int* deg) {
  int i = blockIdx.x * blockDim.x + threadIdx.x;
  if (i < NN) deg[i] = 1;  // self loop
}

__global__ void k_count(const int* __restrict__ dst, int E0, int* deg) {
  int i = blockIdx.x * blockDim.x + threadIdx.x;
  if (i < E0) atomicAdd(&deg[dst[i]], 1);
}

// parallel 3-phase exclusive scan over deg -> offs (+ cursor copy in phase C)
__global__ __launch_bounds__(256) void k_scanA(const int* __restrict__ deg, int* offs,
                                               int* bsum) {
  __shared__ int wsum[4];
  int tid = threadIdx.x;
  int lane = tid & 63;
  int wv = tid >> 6;
  int i = blockIdx.x * 1024 + tid * 4;
  int4 v = make_int4(0, 0, 0, 0);
  if (i + 3 < NN) {
    v = *(const int4*)(deg + i);
  } else {
    if (i + 0 < NN) v.x = deg[i + 0];
    if (i + 1 < NN) v.y = deg[i + 1];
    if (i + 2 < NN) v.z = deg[i + 2];
    if (i + 3 < NN) v.w = deg[i + 3];
  }
  int tot = v.x + v.y + v.z + v.w;
  int s = tot;
  #pragma unroll
  for (int o = 1; o < 64; o <<= 1) {
    int t = __shfl_up(s, o);
    if (lane >= o) s += t;
  }
  if (lane == 63) wsum[wv] = s;
  __syncthreads();
  int base = 0;
  #pragma unroll
  for (int w2 = 0; w2 < 4; w2++)
    if (w2 < wv) base += wsum[w2];
  int p = base + s - tot;
  if (i + 0 < NN) { offs[i + 0] = p; p += v.x; }
  if (i + 1 < NN) { offs[i + 1] = p; p += v.y; }
  if (i + 2 < NN) { offs[i + 2] = p; p += v.z; }
  if (i + 3 < NN) { offs[i + 3] = p; }
  if (tid == 255) bsum[blockIdx.x] = base + s;
}

__global__ void k_scanB(const int* __restrict__ bsum, int* bbase, int* offs, int nb) {
  int lane = threadIdx.x;  // 64 threads, nb <= 64
  int v = (lane < nb) ? bsum[lane] : 0;
  int s = v;
  #pragma unroll
  for (int o = 1; o < 64; o <<= 1) {
    int t = __shfl_up(s, o);
    if (lane >= o) s += t;
  }
  if (lane < nb) bbase[lane] = s - v;
  if (lane == 63) offs[NN] = s;
}

__global__ __launch_bounds__(256) void k_scanC(int* offs, int* cursor,
                                               const int* __restrict__ bbase) {
  int add = bbase[blockIdx.x];
  int i = blockIdx.x * 1024 + threadIdx.x * 4;
  #pragma unroll
  for (int j = 0; j < 4; j++) {
    if (i + j < NN) {
      int o = offs[i + j] + add;
      offs[i + j] = o;
      cursor[i + j] = o;
    }
  }
}

__global__ void k_scatter(const int* __restrict__ src, const int* __restrict__ dst,
                          int E0, int* cursor, int* __restrict__ nbr) {
  int i = blockIdx.x * blockDim.x + threadIdx.x;
  if (i < E0) {
    int pos = atomicAdd(&cursor[dst[i]], 1);
    nbr[pos] = src[i];
  } else if (i < E0 + NN) {
    int v = i - E0;
    int pos = atomicAdd(&cursor[v], 1);
    nbr[pos] = v;
  }
}

// ---------------- casts ----------------
__global__ void k_cast4(const float* __restrict__ in, unsigned short* __restrict__ out,
                        int n4) {
  int i = blockIdx.x * blockDim.x + threadIdx.x;
  if (i >= n4) return;
  float4 v = *(const float4*)(in + (size_t)i * 4);
  ushort4 o;
  o.x = f2bf(v.x); o.y = f2bf(v.y); o.z = f2bf(v.z); o.w = f2bf(v.w);
  *(ushort4*)(out + (size_t)i * 4) = o;
}

__global__ void k_castWt(const float* __restrict__ W, unsigned short* __restrict__ Wt,
                         int K, int cols) {
  int i = blockIdx.x * blockDim.x + threadIdx.x;
  if (i >= K * cols) return;
  int k = i / cols, c = i % cols;
  Wt[(size_t)c * K + k] = f2bf(W[i]);
}

__global__ void k_castWt_perm(const float* __restrict__ W, unsigned short* __restrict__ Wt,
                              int K) {
  int i = blockIdx.x * blockDim.x + threadIdx.x;
  if (i >= K * NHEADS * NCLASS) return;
  int k = i / (NHEADS * NCLASS);
  int rem = i % (NHEADS * NCLASS);
  int h = rem / NCLASS, c = rem % NCLASS;
  Wt[(size_t)(c * NHEADS + h) * K + k] = f2bf(W[i]);
}

// ---------------- bf16 MFMA GEMM, dual output: bf16 + fp8 (layer 1) ----------------
__global__ __launch_bounds__(256) void k_gemm_bf_dual(const unsigned short* __restrict__ A,
                                                      const unsigned short* __restrict__ Bt,
                                                      unsigned short* __restrict__ C,
                                                      unsigned char* __restrict__ C8,
                                                      int rows, int K, int cols) {
  __shared__ unsigned short Bs[256 * 40];  // 20 KB
  int t = threadIdx.x;
  int wave = t >> 6, lane = t & 63;
  int quad = lane >> 4, sixt = lane & 15;
  int rb = blockIdx.x * 64 + (wave >> 1) * 32;
  int cw = (wave & 1) * 128;
  int cbw = blockIdx.y * 256 + cw;
  int r0 = rb + sixt, r1 = rb + 16 + sixt;
  const unsigned short* Ap0 = A + (size_t)(r0 < rows ? r0 : 0) * K + quad * 8;
  const unsigned short* Ap1 = A + (size_t)(r1 < rows ? r1 : 0) * K + quad * 8;
  const unsigned short* Bg = Bt + (size_t)(blockIdx.y * 256 + (t >> 2)) * K + (t & 3) * 8;
  const size_t BgStep = (size_t)64 * K;
  char* BsW = (char*)Bs + (t >> 2) * 80 + (t & 3) * 16;
  f32x4 acc0[8] = {}, acc1[8] = {};
  for (int k0 = 0; k0 < K; k0 += 32) {
    uint4 v0 = *(const uint4*)(Bg + k0);
    uint4 v1 = *(const uint4*)(Bg + BgStep + k0);
    uint4 v2 = *(const uint4*)(Bg + 2 * BgStep + k0);
    uint4 v3 = *(const uint4*)(Bg + 3 * BgStep + k0);
    bf16x8 a0 = *(const bf16x8*)(Ap0 + k0);
    bf16x8 a1 = *(const bf16x8*)(Ap1 + k0);
    *(uint4*)(BsW) = v0;
    *(uint4*)(BsW + 64 * 80) = v1;
    *(uint4*)(BsW + 128 * 80) = v2;
    *(uint4*)(BsW + 192 * 80) = v3;
    __syncthreads();
    #pragma unroll
    for (int g = 0; g < 8; g++) {
      bf16x8 b = *(const bf16x8*)((const char*)Bs + (cw + g * 16 + sixt) * 80 + quad * 16);
      acc0[g] = __builtin_amdgcn_mfma_f32_16x16x32_bf16(a0, b, acc0[g], 0, 0, 0);
      acc1[g] = __builtin_amdgcn_mfma_f32_16x16x32_bf16(a1, b, acc1[g], 0, 0, 0);
    }
    __syncthreads();
  }
  #pragma unroll
  for (int r = 0; r < 4; r++) {
    int row = rb + quad * 4 + r;
    if (row < rows) {
      unsigned short* out = C + (size_t)row * cols + cbw + sixt;
      unsigned char* out8 = C8 + (size_t)row * cols + cbw + sixt;
      #pragma unroll
      for (int g = 0; g < 8; g++) {
        out[g * 16] = f2bf(acc0[g][r]);
        int wq = __builtin_amdgcn_cvt_pk_fp8_f32(acc0[g][r], acc0[g][r], 0, false);
        out8[g * 16] = (unsigned char)(wq & 0xff);
      }
    }
    int row2 = row + 16;
    if (row2 < rows) {
      unsigned short* out = C + (size_t)row2 * cols + cbw + sixt;
      unsigned char* out8 = C8 + (size_t)row2 * cols + cbw + sixt;
      #pragma unroll
      for (int g = 0; g < 8; g++) {
        out[g * 16] = f2bf(acc1[g][r]);
        int wq = __builtin_amdgcn_cvt_pk_fp8_f32(acc1[g][r], acc1[g][r], 0, false);
        out8[g * 16] = (unsigned char)(wq & 0xff);
      }
    }
  }
}

// ---------------- same GEMM, fp8 e4m3 output only (layer 2) ----------------
__global__ __launch_bounds__(256) void k_gemm_bf8(const unsigned short* __restrict__ A,
                                                  const unsigned short* __restrict__ Bt,
                                                  unsigned char* __restrict__ C,
                                                  int rows, int K, int cols) {
  __shared__ unsigned short Bs[256 * 40];  // 20 KB
  int t = threadIdx.x;
  int wave = t >> 6, lane = t & 63;
  int quad = lane >> 4, sixt = lane & 15;
  int rb = blockIdx.x * 64 + (wave >> 1) * 32;
  int cw = (wave & 1) * 128;
  int cbw = blockIdx.y * 256 + cw;
  int r0 = rb + sixt, r1 = rb + 16 + sixt;
  const unsigned short* Ap0 = A + (size_t)(r0 < rows ? r0 : 0) * K + quad * 8;
  const unsigned short* Ap1 = A + (size_t)(r1 < rows ? r1 : 0) * K + quad * 8;
  const unsigned short* Bg = Bt + (size_t)(blockIdx.y * 256 + (t >> 2)) * K + (t & 3) * 8;
  const size_t BgStep = (size_t)64 * K;
  char* BsW = (char*)Bs + (t >> 2) * 80 + (t & 3) * 16;
  f32x4 acc0[8] = {}, acc1[8] = {};
  for (int k0 = 0; k0 < K; k0 += 32) {
    uint4 v0 = *(const uint4*)(Bg + k0);
    uint4 v1 = *(const uint4*)(Bg + BgStep + k0);
    uint4 v2 = *(const uint4*)(Bg + 2 * BgStep + k0);
    uint4 v3 = *(const uint4*)(Bg + 3 * BgStep + k0);
    bf16x8 a0 = *(const bf16x8*)(Ap0 + k0);
    bf16x8 a1 = *(const bf16x8*)(Ap1 + k0);
    *(uint4*)(BsW) = v0;
    *(uint4*)(BsW + 64 * 80) = v1;
    *(uint4*)(BsW + 128 * 80) = v2;
    *(uint4*)(BsW + 192 * 80) = v3;
    __syncthreads();
    #pragma unroll
    for (int g = 0; g < 8; g++) {
      bf16x8 b = *(const bf16x8*)((const char*)Bs + (cw + g * 16 + sixt) * 80 + quad * 16);
      acc0[g] = __builtin_amdgcn_mfma_f32_16x16x32_bf16(a0, b, acc0[g], 0, 0, 0);
      acc1[g] = __builtin_amdgcn_mfma_f32_16x16x32_bf16(a1, b, acc1[g], 0, 0, 0);
    }
    __syncthreads();
  }
  #pragma unroll
  for (int r = 0; r < 4; r++) {
    int row = rb + quad * 4 + r;
    if (row < rows) {
      unsigned char* out = C + (size_t)row * cols + cbw + sixt;
      #pragma unroll
      for (int g = 0; g < 8; g++) {
        int wq = __builtin_amdgcn_cvt_pk_fp8_f32(acc0[g][r], acc0[g][r], 0, false);
        out[g * 16] = (unsigned char)(wq & 0xff);
      }
    }
    int row2 = row + 16;
    if (row2 < rows) {
      unsigned char* out = C + (size_t)row2 * cols + cbw + sixt;
      #pragma unroll
      for (int g = 0; g < 8; g++) {
        int wq = __builtin_amdgcn_cvt_pk_fp8_f32(acc1[g][r], acc1[g][r], 0, false);
        out[g * 16] = (unsigned char)(wq & 0xff);
      }
    }
  }
}

// ---------------- edge-score dots, contiguous layout (layer 1) ----------------
template <int C>
__global__ void k_escore_c(const unsigned short* __restrict__ h,
                           const float* __restrict__ asr, const float* __restrict__ ads,
                           float* __restrict__ es, float* __restrict__ ed) {
  int idx = blockIdx.x * blockDim.x + threadIdx.x;  // n*8 + head
  if (idx >= NN * NHEADS) return;
  int hd = idx & 7;
  const unsigned short* row = h + (size_t)idx * C;
  float s = 0.f, d = 0.f;
  #pragma unroll
  for (int c8 = 0; c8 < C / 8; c8++) {
    uint4 raw = *(const uint4*)(row + c8 * 8);
    float2 p0 = bfpair(raw.x), p1 = bfpair(raw.y), p2 = bfpair(raw.z), p3 = bfpair(raw.w);
    const float* as_ = asr + hd * C + c8 * 8;
    const float* ad_ = ads + hd * C + c8 * 8;
    s += p0.x * as_[0] + p0.y * as_[1] + p1.x * as_[2] + p1.y * as_[3] +
         p2.x * as_[4] + p2.y * as_[5] + p3.x * as_[6] + p3.y * as_[7];
    d += p0.x * ad_[0] + p0.y * ad_[1] + p1.x * ad_[2] + p1.y * ad_[3] +
         p2.x * ad_[4] + p2.y * ad_[5] + p3.x * ad_[6] + p3.y * ad_[7];
  }
  es[idx] = s;
  ed[idx] = d;
}

// ---------------- edge-score dots, permuted fp8 layout (layer 2) ----------------
__global__ void k_escore_p8(const unsigned char* __restrict__ h,
                            const float* __restrict__ asr, const float* __restrict__ ads,
                            float* __restrict__ es, float* __restrict__ ed) {
  int idx = blockIdx.x * blockDim.x + threadIdx.x;  // n*8 + head
  if (idx >= NN * NHEADS) return;
  int hd = idx & 7;
  int n = idx >> 3;
  const unsigned short* rp =
      (const unsigned short*)(h + (size_t)n * (NHEADS * NCLASS) + (hd & ~1));
  int hi = hd & 1;
  float s = 0.f, d = 0.f;
  #pragma unroll
  for (int c = 0; c < NCLASS; c++) {
    unsigned short w = rp[c * 4];
    f32x2 q = __builtin_amdgcn_cvt_pk_f32_fp8((int)w, false);
    float v = hi ? q.y : q.x;
    s += v * asr[hd * NCLASS + c];
    d += v * ads[hd * NCLASS + c];
  }
  es[idx] = s;
  ed[idx] = d;
}

// ---------------- fused single-pass online-softmax + layer-1 aggregation ----------
// R3 structure widened to 16-edge groups: 16 fp8 rows (4 B/lane) in flight per drain.
__global__ __launch_bounds__(256) void k_agg1f(const int* __restrict__ offs,
                                               const int* __restrict__ nbr,
                                               const unsigned char* __restrict__ h1f8,
                                               const float* __restrict__ es,
                                               const float* __restrict__ ed,
                                               const float* __restrict__ b1,
                                               unsigned short* __restrict__ out) {
  int node = blockIdx.x * 4 + (threadIdx.x >> 6);
  if (node >= NN) return;
  int lane = threadIdx.x & 63;
  int h = lane & 7;
  int sub = lane >> 3;  // coef-phase edge slot (and slot+8); consume-phase head
  int col = lane << 2;  // consume-phase 4 channels
  int beg = offs[node], end = offs[node + 1];
  float edst = ed[node * NHEADS + h];
  int kb = beg;
  int i0 = kb + (lane & 15); if (i0 > end - 1) i0 = end - 1;
  int vt = gld32i(nbr + i0);
  int vtN = 0;
  if (kb + 16 < end) {
    int i1 = kb + 16 + (lane & 15); if (i1 > end - 1) i1 = end - 1;
    vtN = gld32i(nbr + i1);
  }
  VMCNT0();
  int se[16];
  #pragma unroll
  for (int e = 0; e < 16; e++) se[e] = __shfl(vt, e);
  float esv0, esv1;
  {
    int sv0 = __shfl(vt, sub);
    int sv1 = __shfl(vt, sub + 8);
    esv0 = gld32f(es + (size_t)sv0 * NHEADS + h);
    esv1 = gld32f(es + (size_t)sv1 * NHEADS + h);
  }
  VMCNT0();
  float m = -1e30f, z = 0.f;
  float4 acc = make_float4(0.f, 0.f, 0.f, 0.f);
  while (true) {
    int cnt = end - kb; if (cnt > 16) cnt = 16;
    int r[16];
    #pragma unroll
    for (int e = 0; e < 16; e++)
      if (e < cnt) r[e] = gld32i(h1f8 + (size_t)se[e] * NHID + col);
    bool more = kb + 16 < end, more2 = kb + 32 < end;
    int vt2 = 0;
    if (more2) {
      int iC = kb + 32 + (lane & 15); if (iC > end - 1) iC = end - 1;
      vt2 = gld32i(nbr + iC);
    }
    float esvN0 = 0.f, esvN1 = 0.f;
    if (more) {
      int sv0 = __shfl(vtN, sub);
      int sv1 = __shfl(vtN, sub + 8);
      esvN0 = gld32f(es + (size_t)sv0 * NHEADS + h);
      esvN1 = gld32f(es + (size_t)sv1 * NHEADS + h);
    }
    // coef phase for 16 edges (2 per lane), overlaps in-flight gathers
    float ar0 = esv0 + edst;
    ar0 = (ar0 > 0.f) ? ar0 : 0.2f * ar0;
    float a0 = (kb + sub < end) ? ar0 : -1e30f;
    float ar1 = esv1 + edst;
    ar1 = (ar1 > 0.f) ? ar1 : 0.2f * ar1;
    float a1 = (kb + sub + 8 < end) ? ar1 : -1e30f;
    float gm = fmaxf(a0, a1);
    #pragma unroll
    for (int o = 8; o < 64; o <<= 1) gm = fmaxf(gm, __shfl_xor(gm, o));
    float mn = fmaxf(m, gm);
    float ee0 = __expf(a0 - mn);
    float ee1 = __expf(a1 - mn);
    float zg = ee0 + ee1;
    #pragma unroll
    for (int o = 8; o < 64; o <<= 1) zg += __shfl_xor(zg, o);
    float sc = __expf(m - mn);
    z = z * sc + zg;
    m = mn;
    VMCNT0();
    // rescale + consume (fp8 decode)
    float sch = __shfl(sc, sub);
    acc.x *= sch; acc.y *= sch; acc.z *= sch; acc.w *= sch;
    #pragma unroll
    for (int e = 0; e < 16; e++) {
      if (e < cnt) {
        float ce = (e < 8) ? __shfl(ee0, e * 8 + sub) : __shfl(ee1, (e - 8) * 8 + sub);
        f32x2 q0 = __builtin_amdgcn_cvt_pk_f32_fp8(r[e], false);
        f32x2 q1 = __builtin_amdgcn_cvt_pk_f32_fp8(r[e], true);
        acc.x += ce * q0.x;
        acc.y += ce * q0.y;
        acc.z += ce * q1.x;
        acc.w += ce * q1.y;
      }
    }
    if (!more) break;
    kb += 16;
    #pragma unroll
    for (int e = 0; e < 16; e++) se[e] = __shfl(vtN, e);
    esv0 = esvN0;
    esv1 = esvN1;
    vtN = vt2;
  }
  float inv = 1.f / z;
  float ivh = __shfl(inv, sub);
  ushort4 o;
  o.x = f2bf(fmaxf(acc.x * ivh + b1[col + 0], 0.f));
  o.y = f2bf(fmaxf(acc.y * ivh + b1[col + 1], 0.f));
  o.z = f2bf(fmaxf(acc.z * ivh + b1[col + 2], 0.f));
  o.w = f2bf(fmaxf(acc.w * ivh + b1[col + 3], 0.f));
  *(ushort4*)(out + (size_t)node * NHID + col) = o;
}

// ---------------- fused single-pass online-softmax + layer-2 agg + mean + lsm ------
// R3 structure widened to 16-edge groups: 16 fp8 rows (8 B/lane) in flight per drain.
__global__ __launch_bounds__(256) void k_agg2f(const int* __restrict__ offs,
                                               const int* __restrict__ nbr,
                                               const unsigned char* __restrict__ h2f8,
                                               const float* __restrict__ es,
                                               const float* __restrict__ ed,
                                               const float* __restrict__ b2,
                                               float* __restrict__ out) {
  __shared__ __align__(16) float cs[4][128];
  int wv = threadIdx.x >> 6;
  int node = blockIdx.x * 4 + wv;
  if (node >= NN) return;
  int lane = threadIdx.x & 63;
  int h = lane & 7;
  int sub = lane >> 3;
  int beg = offs[node], end = offs[node + 1];
  float edst = ed[node * NHEADS + h];
  int kb = beg;
  int i0 = kb + (lane & 15); if (i0 > end - 1) i0 = end - 1;
  int vt = gld32i(nbr + i0);
  int vtN = 0;
  if (kb + 16 < end) {
    int i1 = kb + 16 + (lane & 15); if (i1 > end - 1) i1 = end - 1;
    vtN = gld32i(nbr + i1);
  }
  VMCNT0();
  int se[16];
  #pragma unroll
  for (int e = 0; e < 16; e++) se[e] = __shfl(vt, e);
  float esv0, esv1;
  {
    int sv0 = __shfl(vt, sub);
    int sv1 = __shfl(vt, sub + 8);
    esv0 = gld32f(es + (size_t)sv0 * NHEADS + h);
    esv1 = gld32f(es + (size_t)sv1 * NHEADS + h);
  }
  VMCNT0();
  float m = -1e30f, z = 0.f;
  float acc[8] = {};
  while (true) {
    int cnt = end - kb; if (cnt > 16) cnt = 16;
    u32x2 r[16];
    #pragma unroll
    for (int e = 0; e < 16; e++)
      if (e < cnt) r[e] = gld64(h2f8 + (size_t)se[e] * (NHEADS * NCLASS) + (lane << 3));
    bool more = kb + 16 < end, more2 = kb + 32 < end;
    int vt2 = 0;
    if (more2) {
      int iC = kb + 32 + (lane & 15); if (iC > end - 1) iC = end - 1;
      vt2 = gld32i(nbr + iC);
    }
    float esvN0 = 0.f, esvN1 = 0.f;
    if (more) {
      int sv0 = __shfl(vtN, sub);
      int sv1 = __shfl(vtN, sub + 8);
      esvN0 = gld32f(es + (size_t)sv0 * NHEADS + h);
      esvN1 = gld32f(es + (size_t)sv1 * NHEADS + h);
    }
    // coef phase for 16 edges (2 per lane), overlaps in-flight gathers
    float ar0 = esv0 + edst;
    ar0 = (ar0 > 0.f) ? ar0 : 0.2f * ar0;
    float a0 = (kb + sub < end) ? ar0 : -1e30f;
    float ar1 = esv1 + edst;
    ar1 = (ar1 > 0.f) ? ar1 : 0.2f * ar1;
    float a1 = (kb + sub + 8 < end) ? ar1 : -1e30f;
    float gm = fmaxf(a0, a1);
    #pragma unroll
    for (int o = 8; o < 64; o <<= 1) gm = fmaxf(gm, __shfl_xor(gm, o));
    float mn = fmaxf(m, gm);
    float ee0 = __expf(a0 - mn);
    float ee1 = __expf(a1 - mn);
    float zg = ee0 + ee1;
    #pragma unroll
    for (int o = 8; o < 64; o <<= 1) zg += __shfl_xor(zg, o);
    float sc = __expf(m - mn);
    z = z * sc + zg;
    m = mn;
    cs[wv][lane] = ee0;       // edge sub,   head h  -> slot sub*8+h
    cs[wv][64 + lane] = ee1;  // edge sub+8, head h  -> slot (sub+8)*8+h
    VMCNT0();
    // rescale + consume (fp8 decode)
    #pragma unroll
    for (int hh = 0; hh < 8; hh++) acc[hh] *= __shfl(sc, hh);
    #pragma unroll
    for (int e = 0; e < 16; e++) {
      if (e < cnt) {
        float4 cA = *(const float4*)&cs[wv][e * 8];
        float4 cB = *(const float4*)&cs[wv][e * 8 + 4];
        f32x2 q0 = __builtin_amdgcn_cvt_pk_f32_fp8((int)r[e][0], false);
        f32x2 q1 = __builtin_amdgcn_cvt_pk_f32_fp8((int)r[e][0], true);
        f32x2 q2 = __builtin_amdgcn_cvt_pk_f32_fp8((int)r[e][1], false);
        f32x2 q3 = __builtin_amdgcn_cvt_pk_f32_fp8((int)r[e][1], true);
        acc[0] += cA.x * q0.x;
        acc[1] += cA.y * q0.y;
        acc[2] += cA.z * q1.x;
        acc[3] += cA.w * q1.y;
        acc[4] += cB.x * q2.x;
        acc[5] += cB.y * q2.y;
        acc[6] += cB.z * q3.x;
        acc[7] += cB.w * q3.y;
      }
    }
    if (!more) break;
    kb += 16;
    #pragma unroll
    for (int e = 0; e < 16; e++) se[e] = __shfl(vtN, e);
    esv0 = esvN0;
    esv1 = esvN1;
    vtN = vt2;
  }
  float inv = 1.f / z;
  float val = 0.f;
  #pragma unroll
  for (int hh = 0; hh < 8; hh++) val += acc[hh] * __shfl(inv, hh);
  val = val * 0.125f + b2[lane];
  float mx = val;
  #pragma unroll
  for (int o = 32; o > 0; o >>= 1) mx = fmaxf(mx, __shfl_xor(mx, o));
  float ex = __expf(val - mx);
  float sm = ex;
  #pragma unroll
  for (int o = 32; o > 0; o >>= 1) sm += __shfl_xor(sm, o);
  out[(size_t)node * NCLASS + lane] = val - mx - __logf(sm);
}

// ---------------- launch ----------------
extern "C" void kernel_launch(void* const* d_in, const int* in_sizes, int n_in,
                              void* d_out, int out_size, void* d_ws, size_t ws_size,
                              hipStream_t stream) {
  const float* x   = (const float*)d_in[0];
  const int* eidx  = (const int*)d_in[1];
  const float* W1  = (const float*)d_in[2];
  const float* a1s = (const float*)d_in[3];
  const float* a1d = (const float*)d_in[4];
  const float* b1  = (const float*)d_in[5];
  const float* W2  = (const float*)d_in[6];
  const float* a2s = (const float*)d_in[7];
  const float* a2d = (const float*)d_in[8];
  const float* b2  = (const float*)d_in[9];
  const int E0 = in_sizes[1] / 2;
  const int* esrc = eidx;
  const int* edst = eidx + E0;
  const int E = E0 + NN;

  char* w = (char*)d_ws;
  auto carve = [&](size_t bytes) {
    void* p = (void*)w;
    w += (bytes + 255) & ~(size_t)255;
    return p;
  };
  int* deg      = (int*)carve((size_t)NN * 4);
  int* offs     = (int*)carve((size_t)(NN + 1) * 4);
  int* cursor   = (int*)carve((size_t)NN * 4);
  int* nbr      = (int*)carve((size_t)E * 4);
  int* bsum     = (int*)carve((size_t)64 * 4);
  int* bbase    = (int*)carve((size_t)64 * 4);
  float* es1    = (float*)carve((size_t)NN * NHEADS * 4);
  float* ed1    = (float*)carve((size_t)NN * NHEADS * 4);
  unsigned short* xbf   = (unsigned short*)carve((size_t)NN * NF * 2);
  unsigned short* W1t   = (unsigned short*)carve((size_t)NF * NHID * 2);
  unsigned short* W2t   = (unsigned short*)carve((size_t)NHID * NHEADS * NCLASS * 2);
  unsigned short* h1b   = (unsigned short*)carve((size_t)NN * NHID * 2);
  unsigned short* out1b = (unsigned short*)carve((size_t)NN * NHID * 2);
  unsigned char* h1f8   = (unsigned char*)carve((size_t)NN * NHID);
  // fp8 h2 (written directly by GEMM2) reuses the xbf buffer (dead after GEMM1)
  unsigned char* h2f8 = (unsigned char*)xbf;

  // CSR build (parallel scan)
  k_init_deg<<<(NN + 255) / 256, 256, 0, stream>>>(deg);
  k_count<<<(E0 + 255) / 256, 256, 0, stream>>>(edst, E0, deg);
  k_scanA<<<SCAN_NBLK, 256, 0, stream>>>(deg, offs, bsum);
  k_scanB<<<1, 64, 0, stream>>>(bsum, bbase, offs, SCAN_NBLK);
  k_scanC<<<SCAN_NBLK, 256, 0, stream>>>(offs, cursor, bbase);
  k_scatter<<<(E0 + NN + 255) / 256, 256, 0, stream>>>(esrc, edst, E0, cursor, nbr);

  // casts
  k_cast4<<<(NN * NF / 4 + 255) / 256, 256, 0, stream>>>(x, xbf, NN * NF / 4);
  k_castWt<<<(NF * NHID + 255) / 256, 256, 0, stream>>>(W1, W1t, NF, NHID);
  k_castWt_perm<<<(NHID * NHEADS * NCLASS + 255) / 256, 256, 0, stream>>>(W2, W2t, NHID);

  // layer 1 (GEMM writes bf16 for escore + fp8 for the gather)
  k_gemm_bf_dual<<<dim3((NN + 63) / 64, NHID / 256), 256, 0, stream>>>(
      xbf, W1t, h1b, h1f8, NN, NF, NHID);
  k_escore_c<32><<<(NN * NHEADS + 255) / 256, 256, 0, stream>>>(h1b, a1s, a1d, es1, ed1);
  k_agg1f<<<(NN + 3) / 4, 256, 0, stream>>>(offs, nbr, h1f8, es1, ed1, b1, out1b);

  // layer 2 (GEMM writes fp8 directly; escore reads fp8)
  k_gemm_bf8<<<dim3((NN + 63) / 64, (NHEADS * NCLASS) / 256), 256, 0, stream>>>(
      out1b, W2t, h2f8, NN, NHID, NHEADS * NCLASS);
  k_escore_p8<<<(NN * NHEADS + 255) / 256, 256, 0, stream>>>(h2f8, a2s, a2d, es1, ed1);
  k_agg2f<<<(NN + 3) / 4, 256, 0, stream>>>(offs, nbr, h2f8, es1, ed1, b2,
                                            (float*)d_out);
}

// Round 9
// 523.144 us; speedup vs baseline: 1.2219x; 1.0329x over previous
//
#include <hip/hip_runtime.h>
#include <math.h>

#define NN 50000
#define NF 512
#define NHID 256
#define NCLASS 64
#define NHEADS 8
#define SCAN_NBLK ((NN + 1023) / 1024)

typedef __attribute__((ext_vector_type(8))) short bf16x8;
typedef __attribute__((ext_vector_type(4))) float f32x4;
typedef __attribute__((ext_vector_type(2))) float f32x2;
typedef __attribute__((ext_vector_type(2))) unsigned int u32x2;

static __device__ __forceinline__ unsigned short f2bf(float f) {
  unsigned int u = __float_as_uint(f);
  unsigned int r = (u + 0x7fffu + ((u >> 16) & 1u)) >> 16;
  return (unsigned short)r;
}
static __device__ __forceinline__ float bf2f(unsigned short u) {
  return __uint_as_float(((unsigned int)u) << 16);
}
static __device__ __forceinline__ float2 bfpair(unsigned int u) {
  return make_float2(__uint_as_float(u << 16), __uint_as_float(u & 0xffff0000u));
}

// pack 8 f32 -> 8 bf16 via v_cvt_pk_bf16_f32 (RNE, 4 instrs)
static __device__ __forceinline__ bf16x8 cvt8(float4 lo, float4 hi) {
  unsigned int w0, w1, w2, w3;
  asm("v_cvt_pk_bf16_f32 %0, %1, %2" : "=v"(w0) : "v"(lo.x), "v"(lo.y));
  asm("v_cvt_pk_bf16_f32 %0, %1, %2" : "=v"(w1) : "v"(lo.z), "v"(lo.w));
  asm("v_cvt_pk_bf16_f32 %0, %1, %2" : "=v"(w2) : "v"(hi.x), "v"(hi.y));
  asm("v_cvt_pk_bf16_f32 %0, %1, %2" : "=v"(w3) : "v"(hi.z), "v"(hi.w));
  union { unsigned int u[4]; bf16x8 b; } p;
  p.u[0] = w0; p.u[1] = w1; p.u[2] = w2; p.u[3] = w3;
  return p.b;
}

// ---- inline-asm gathers: compiler tracks zero vmem in hot loops ----
static __device__ __forceinline__ u32x2 gld64(const void* p) {
  u32x2 r;
  asm volatile("global_load_dwordx2 %0, %1, off"
               : "=v"(r) : "v"((unsigned long long)p));
  return r;
}
static __device__ __forceinline__ int gld32i(const void* p) {
  int r;
  asm volatile("global_load_dword %0, %1, off"
               : "=v"(r) : "v"((unsigned long long)p));
  return r;
}
static __device__ __forceinline__ float gld32f(const void* p) {
  float r;
  asm volatile("global_load_dword %0, %1, off"
               : "=v"(r) : "v"((unsigned long long)p));
  return r;
}
#define VMCNT0()                                        \
  do {                                                  \
    asm volatile("s_waitcnt vmcnt(0)" ::: "memory");    \
    __builtin_amdgcn_sched_barrier(0);                  \
  } while (0)

// ---------------- CSR build ----------------
__global__ void k_init_deg(int* deg) {
  int i = blockIdx.x * blockDim.x + threadIdx.x;
  if (i < NN) deg[i] = 1;  // self loop
}

__global__ void k_count(const int* __restrict__ dst, int E0, int* deg) {
  int i = blockIdx.x * blockDim.x + threadIdx.x;
  if (i < E0) atomicAdd(&deg[dst[i]], 1);
}

// parallel 3-phase exclusive scan over deg -> offs (+ cursor copy in phase C)
__global__ __launch_bounds__(256) void k_scanA(const int* __restrict__ deg, int* offs,
                                               int* bsum) {
  __shared__ int wsum[4];
  int tid = threadIdx.x;
  int lane = tid & 63;
  int wv = tid >> 6;
  int i = blockIdx.x * 1024 + tid * 4;
  int4 v = make_int4(0, 0, 0, 0);
  if (i + 3 < NN) {
    v = *(const int4*)(deg + i);
  } else {
    if (i + 0 < NN) v.x = deg[i + 0];
    if (i + 1 < NN) v.y = deg[i + 1];
    if (i + 2 < NN) v.z = deg[i + 2];
    if (i + 3 < NN) v.w = deg[i + 3];
  }
  int tot = v.x + v.y + v.z + v.w;
  int s = tot;
  #pragma unroll
  for (int o = 1; o < 64; o <<= 1) {
    int t = __shfl_up(s, o);
    if (lane >= o) s += t;
  }
  if (lane == 63) wsum[wv] = s;
  __syncthreads();
  int base = 0;
  #pragma unroll
  for (int w2 = 0; w2 < 4; w2++)
    if (w2 < wv) base += wsum[w2];
  int p = base + s - tot;
  if (i + 0 < NN) { offs[i + 0] = p; p += v.x; }
  if (i + 1 < NN) { offs[i + 1] = p; p += v.y; }
  if (i + 2 < NN) { offs[i + 2] = p; p += v.z; }
  if (i + 3 < NN) { offs[i + 3] = p; }
  if (tid == 255) bsum[blockIdx.x] = base + s;
}

__global__ void k_scanB(const int* __restrict__ bsum, int* bbase, int* offs, int nb) {
  int lane = threadIdx.x;  // 64 threads, nb <= 64
  int v = (lane < nb) ? bsum[lane] : 0;
  int s = v;
  #pragma unroll
  for (int o = 1; o < 64; o <<= 1) {
    int t = __shfl_up(s, o);
    if (lane >= o) s += t;
  }
  if (lane < nb) bbase[lane] = s - v;
  if (lane == 63) offs[NN] = s;
}

__global__ __launch_bounds__(256) void k_scanC(int* offs, int* cursor,
                                               const int* __restrict__ bbase) {
  int add = bbase[blockIdx.x];
  int i = blockIdx.x * 1024 + threadIdx.x * 4;
  #pragma unroll
  for (int j = 0; j < 4; j++) {
    if (i + j < NN) {
      int o = offs[i + j] + add;
      offs[i + j] = o;
      cursor[i + j] = o;
    }
  }
}

__global__ void k_scatter(const int* __restrict__ src, const int* __restrict__ dst,
                          int E0, int* cursor, int* __restrict__ nbr) {
  int i = blockIdx.x * blockDim.x + threadIdx.x;
  if (i < E0) {
    int pos = atomicAdd(&cursor[dst[i]], 1);
    nbr[pos] = src[i];
  } else if (i < E0 + NN) {
    int v = i - E0;
    int pos = atomicAdd(&cursor[v], 1);
    nbr[pos] = v;
  }
}

// ---------------- weight casts ----------------
__global__ void k_castWt(const float* __restrict__ W, unsigned short* __restrict__ Wt,
                         int K, int cols) {
  int i = blockIdx.x * blockDim.x + threadIdx.x;
  if (i >= K * cols) return;
  int k = i / cols, c = i % cols;
  Wt[(size_t)c * K + k] = f2bf(W[i]);
}

__global__ void k_castWt_perm(const float* __restrict__ W, unsigned short* __restrict__ Wt,
                              int K) {
  int i = blockIdx.x * blockDim.x + threadIdx.x;
  if (i >= K * NHEADS * NCLASS) return;
  int k = i / (NHEADS * NCLASS);
  int rem = i % (NHEADS * NCLASS);
  int h = rem / NCLASS, c = rem % NCLASS;
  Wt[(size_t)(c * NHEADS + h) * K + k] = f2bf(W[i]);
}

// ---- MFMA GEMM, f32 A (cvt_pk in A-load), dual output bf16 + fp8 (layer 1) ----
__global__ __launch_bounds__(256) void k_gemm_f32a_dual(
    const float* __restrict__ A, const unsigned short* __restrict__ Bt,
    unsigned short* __restrict__ C, unsigned char* __restrict__ C8,
    int rows, int K, int cols) {
  __shared__ unsigned short Bs[256 * 40];  // 20 KB
  int t = threadIdx.x;
  int wave = t >> 6, lane = t & 63;
  int quad = lane >> 4, sixt = lane & 15;
  int rb = blockIdx.x * 64 + (wave >> 1) * 32;
  int cw = (wave & 1) * 128;
  int cbw = blockIdx.y * 256 + cw;
  int r0 = rb + sixt, r1 = rb + 16 + sixt;
  const float* Ap0 = A + (size_t)(r0 < rows ? r0 : 0) * K + quad * 8;
  const float* Ap1 = A + (size_t)(r1 < rows ? r1 : 0) * K + quad * 8;
  const unsigned short* Bg = Bt + (size_t)(blockIdx.y * 256 + (t >> 2)) * K + (t & 3) * 8;
  const size_t BgStep = (size_t)64 * K;
  char* BsW = (char*)Bs + (t >> 2) * 80 + (t & 3) * 16;
  f32x4 acc0[8] = {}, acc1[8] = {};
  for (int k0 = 0; k0 < K; k0 += 32) {
    uint4 v0 = *(const uint4*)(Bg + k0);
    uint4 v1 = *(const uint4*)(Bg + BgStep + k0);
    uint4 v2 = *(const uint4*)(Bg + 2 * BgStep + k0);
    uint4 v3 = *(const uint4*)(Bg + 3 * BgStep + k0);
    float4 a0lo = *(const float4*)(Ap0 + k0);
    float4 a0hi = *(const float4*)(Ap0 + k0 + 4);
    float4 a1lo = *(const float4*)(Ap1 + k0);
    float4 a1hi = *(const float4*)(Ap1 + k0 + 4);
    bf16x8 a0 = cvt8(a0lo, a0hi);
    bf16x8 a1 = cvt8(a1lo, a1hi);
    *(uint4*)(BsW) = v0;
    *(uint4*)(BsW + 64 * 80) = v1;
    *(uint4*)(BsW + 128 * 80) = v2;
    *(uint4*)(BsW + 192 * 80) = v3;
    __syncthreads();
    #pragma unroll
    for (int g = 0; g < 8; g++) {
      bf16x8 b = *(const bf16x8*)((const char*)Bs + (cw + g * 16 + sixt) * 80 + quad * 16);
      acc0[g] = __builtin_amdgcn_mfma_f32_16x16x32_bf16(a0, b, acc0[g], 0, 0, 0);
      acc1[g] = __builtin_amdgcn_mfma_f32_16x16x32_bf16(a1, b, acc1[g], 0, 0, 0);
    }
    __syncthreads();
  }
  #pragma unroll
  for (int r = 0; r < 4; r++) {
    int row = rb + quad * 4 + r;
    if (row < rows) {
      unsigned short* out = C + (size_t)row * cols + cbw + sixt;
      unsigned char* out8 = C8 + (size_t)row * cols + cbw + sixt;
      #pragma unroll
      for (int g = 0; g < 8; g++) {
        out[g * 16] = f2bf(acc0[g][r]);
        int wq = __builtin_amdgcn_cvt_pk_fp8_f32(acc0[g][r], acc0[g][r], 0, false);
        out8[g * 16] = (unsigned char)(wq & 0xff);
      }
    }
    int row2 = row + 16;
    if (row2 < rows) {
      unsigned short* out = C + (size_t)row2 * cols + cbw + sixt;
      unsigned char* out8 = C8 + (size_t)row2 * cols + cbw + sixt;
      #pragma unroll
      for (int g = 0; g < 8; g++) {
        out[g * 16] = f2bf(acc1[g][r]);
        int wq = __builtin_amdgcn_cvt_pk_fp8_f32(acc1[g][r], acc1[g][r], 0, false);
        out8[g * 16] = (unsigned char)(wq & 0xff);
      }
    }
  }
}

// ---------------- bf16-A GEMM, fp8 e4m3 output only (layer 2) ----------------
__global__ __launch_bounds__(256) void k_gemm_bf8(const unsigned short* __restrict__ A,
                                                  const unsigned short* __restrict__ Bt,
                                                  unsigned char* __restrict__ C,
                                                  int rows, int K, int cols) {
  __shared__ unsigned short Bs[256 * 40];  // 20 KB
  int t = threadIdx.x;
  int wave = t >> 6, lane = t & 63;
  int quad = lane >> 4, sixt = lane & 15;
  int rb = blockIdx.x * 64 + (wave >> 1) * 32;
  int cw = (wave & 1) * 128;
  int cbw = blockIdx.y * 256 + cw;
  int r0 = rb + sixt, r1 = rb + 16 + sixt;
  const unsigned short* Ap0 = A + (size_t)(r0 < rows ? r0 : 0) * K + quad * 8;
  const unsigned short* Ap1 = A + (size_t)(r1 < rows ? r1 : 0) * K + quad * 8;
  const unsigned short* Bg = Bt + (size_t)(blockIdx.y * 256 + (t >> 2)) * K + (t & 3) * 8;
  const size_t BgStep = (size_t)64 * K;
  char* BsW = (char*)Bs + (t >> 2) * 80 + (t & 3) * 16;
  f32x4 acc0[8] = {}, acc1[8] = {};
  for (int k0 = 0; k0 < K; k0 += 32) {
    uint4 v0 = *(const uint4*)(Bg + k0);
    uint4 v1 = *(const uint4*)(Bg + BgStep + k0);
    uint4 v2 = *(const uint4*)(Bg + 2 * BgStep + k0);
    uint4 v3 = *(const uint4*)(Bg + 3 * BgStep + k0);
    bf16x8 a0 = *(const bf16x8*)(Ap0 + k0);
    bf16x8 a1 = *(const bf16x8*)(Ap1 + k0);
    *(uint4*)(BsW) = v0;
    *(uint4*)(BsW + 64 * 80) = v1;
    *(uint4*)(BsW + 128 * 80) = v2;
    *(uint4*)(BsW + 192 * 80) = v3;
    __syncthreads();
    #pragma unroll
    for (int g = 0; g < 8; g++) {
      bf16x8 b = *(const bf16x8*)((const char*)Bs + (cw + g * 16 + sixt) * 80 + quad * 16);
      acc0[g] = __builtin_amdgcn_mfma_f32_16x16x32_bf16(a0, b, acc0[g], 0, 0, 0);
      acc1[g] = __builtin_amdgcn_mfma_f32_16x16x32_bf16(a1, b, acc1[g], 0, 0, 0);
    }
    __syncthreads();
  }
  #pragma unroll
  for (int r = 0; r < 4; r++) {
    int row = rb + quad * 4 + r;
    if (row < rows) {
      unsigned char* out = C + (size_t)row * cols + cbw + sixt;
      #pragma unroll
      for (int g = 0; g < 8; g++) {
        int wq = __builtin_amdgcn_cvt_pk_fp8_f32(acc0[g][r], acc0[g][r], 0, false);
        out[g * 16] = (unsigned char)(wq & 0xff);
      }
    }
    int row2 = row + 16;
    if (row2 < rows) {
      unsigned char* out = C + (size_t)row2 * cols + cbw + sixt;
      #pragma unroll
      for (int g = 0; g < 8; g++) {
        int wq = __builtin_amdgcn_cvt_pk_fp8_f32(acc1[g][r], acc1[g][r], 0, false);
        out[g * 16] = (unsigned char)(wq & 0xff);
      }
    }
  }
}

// ---------------- edge-score dots, contiguous layout (layer 1) ----------------
template <int C>
__global__ void k_escore_c(const unsigned short* __restrict__ h,
                           const float* __restrict__ asr, const float* __restrict__ ads,
                           float* __restrict__ es, float* __restrict__ ed) {
  int idx = blockIdx.x * blockDim.x + threadIdx.x;  // n*8 + head
  if (idx >= NN * NHEADS) return;
  int hd = idx & 7;
  const unsigned short* row = h + (size_t)idx * C;
  float s = 0.f, d = 0.f;
  #pragma unroll
  for (int c8 = 0; c8 < C / 8; c8++) {
    uint4 raw = *(const uint4*)(row + c8 * 8);
    float2 p0 = bfpair(raw.x), p1 = bfpair(raw.y), p2 = bfpair(raw.z), p3 = bfpair(raw.w);
    const float* as_ = asr + hd * C + c8 * 8;
    const float* ad_ = ads + hd * C + c8 * 8;
    s += p0.x * as_[0] + p0.y * as_[1] + p1.x * as_[2] + p1.y * as_[3] +
         p2.x * as_[4] + p2.y * as_[5] + p3.x * as_[6] + p3.y * as_[7];
    d += p0.x * ad_[0] + p0.y * ad_[1] + p1.x * ad_[2] + p1.y * ad_[3] +
         p2.x * ad_[4] + p2.y * ad_[5] + p3.x * ad_[6] + p3.y * ad_[7];
  }
  es[idx] = s;
  ed[idx] = d;
}

// ---------------- edge-score dots, permuted fp8 layout (layer 2) ----------------
__global__ void k_escore_p8(const unsigned char* __restrict__ h,
                            const float* __restrict__ asr, const float* __restrict__ ads,
                            float* __restrict__ es, float* __restrict__ ed) {
  int idx = blockIdx.x * blockDim.x + threadIdx.x;  // n*8 + head
  if (idx >= NN * NHEADS) return;
  int hd = idx & 7;
  int n = idx >> 3;
  const unsigned short* rp =
      (const unsigned short*)(h + (size_t)n * (NHEADS * NCLASS) + (hd & ~1));
  int hi = hd & 1;
  float s = 0.f, d = 0.f;
  #pragma unroll
  for (int c = 0; c < NCLASS; c++) {
    unsigned short w = rp[c * 4];
    f32x2 q = __builtin_amdgcn_cvt_pk_f32_fp8((int)w, false);
    float v = hi ? q.y : q.x;
    s += v * asr[hd * NCLASS + c];
    d += v * ads[hd * NCLASS + c];
  }
  es[idx] = s;
  ed[idx] = d;
}

// ---------------- fused single-pass online-softmax + layer-1 aggregation ----------
// (R7 validated structure: 8-edge groups, fp8 payload, 4 B/lane)
__global__ __launch_bounds__(256) void k_agg1f(const int* __restrict__ offs,
                                               const int* __restrict__ nbr,
                                               const unsigned char* __restrict__ h1f8,
                                               const float* __restrict__ es,
                                               const float* __restrict__ ed,
                                               const float* __restrict__ b1,
                                               unsigned short* __restrict__ out) {
  int node = blockIdx.x * 4 + (threadIdx.x >> 6);
  if (node >= NN) return;
  int lane = threadIdx.x & 63;
  int h = lane & 7;
  int sub = lane >> 3;  // coef-phase edge slot; ALSO consume-phase head
  int col = lane << 2;  // consume-phase 4 channels
  int beg = offs[node], end = offs[node + 1];
  float edst = ed[node * NHEADS + h];
  int kb = beg;
  int iA = kb + (lane & 7); if (iA > end - 1) iA = end - 1;
  int vt = gld32i(nbr + iA);
  int vtN = 0;
  if (kb + 8 < end) {
    int iB = kb + 8 + (lane & 7); if (iB > end - 1) iB = end - 1;
    vtN = gld32i(nbr + iB);
  }
  VMCNT0();
  int se[8];
  #pragma unroll
  for (int e = 0; e < 8; e++) se[e] = __shfl(vt, e);
  float esv;
  {
    int sv = __shfl(vt, sub);
    esv = gld32f(es + (size_t)sv * NHEADS + h);
  }
  VMCNT0();
  float m = -1e30f, z = 0.f;
  float4 acc = make_float4(0.f, 0.f, 0.f, 0.f);
  while (true) {
    int cnt = end - kb; if (cnt > 8) cnt = 8;
    int r[8];
    #pragma unroll
    for (int e = 0; e < 8; e++)
      if (e < cnt) r[e] = gld32i(h1f8 + (size_t)se[e] * NHID + col);
    bool more = kb + 8 < end, more2 = kb + 16 < end;
    int vt2 = 0;
    if (more2) {
      int iC = kb + 16 + (lane & 7); if (iC > end - 1) iC = end - 1;
      vt2 = gld32i(nbr + iC);
    }
    float esvN = 0.f;
    if (more) {
      int svN = __shfl(vtN, sub);
      esvN = gld32f(es + (size_t)svN * NHEADS + h);
    }
    // coef phase (overlaps in-flight gathers)
    float ar = esv + edst;
    ar = (ar > 0.f) ? ar : 0.2f * ar;
    float a = (kb + sub < end) ? ar : -1e30f;
    float gm = a;
    #pragma unroll
    for (int o = 8; o < 64; o <<= 1) gm = fmaxf(gm, __shfl_xor(gm, o));
    float mn = fmaxf(m, gm);
    float ee = __expf(a - mn);
    float zg = ee;
    #pragma unroll
    for (int o = 8; o < 64; o <<= 1) zg += __shfl_xor(zg, o);
    float sc = __expf(m - mn);
    z = z * sc + zg;
    m = mn;
    VMCNT0();
    // rescale + consume (fp8 decode)
    float sch = __shfl(sc, sub);
    acc.x *= sch; acc.y *= sch; acc.z *= sch; acc.w *= sch;
    #pragma unroll
    for (int e = 0; e < 8; e++) {
      if (e < cnt) {
        float ce = __shfl(ee, e * 8 + sub);  // lane 8e+head: edge e, head==sub
        f32x2 q0 = __builtin_amdgcn_cvt_pk_f32_fp8(r[e], false);
        f32x2 q1 = __builtin_amdgcn_cvt_pk_f32_fp8(r[e], true);
        acc.x += ce * q0.x;
        acc.y += ce * q0.y;
        acc.z += ce * q1.x;
        acc.w += ce * q1.y;
      }
    }
    if (!more) break;
    kb += 8;
    #pragma unroll
    for (int e = 0; e < 8; e++) se[e] = __shfl(vtN, e);
    esv = esvN;
    vtN = vt2;
  }
  float inv = 1.f / z;
  float ivh = __shfl(inv, sub);
  ushort4 o;
  o.x = f2bf(fmaxf(acc.x * ivh + b1[col + 0], 0.f));
  o.y = f2bf(fmaxf(acc.y * ivh + b1[col + 1], 0.f));
  o.z = f2bf(fmaxf(acc.z * ivh + b1[col + 2], 0.f));
  o.w = f2bf(fmaxf(acc.w * ivh + b1[col + 3], 0.f));
  *(ushort4*)(out + (size_t)node * NHID + col) = o;
}

// ---------------- fused single-pass online-softmax + layer-2 agg + mean + lsm ------
// (R7 validated structure: 8-edge groups, fp8 payload, 8 B/lane)
__global__ __launch_bounds__(256) void k_agg2f(const int* __restrict__ offs,
                                               const int* __restrict__ nbr,
                                               const unsigned char* __restrict__ h2f8,
                                               const float* __restrict__ es,
                                               const float* __restrict__ ed,
                                               const float* __restrict__ b2,
                                               float* __restrict__ out) {
  __shared__ __align__(16) float cs[4][64];
  int wv = threadIdx.x >> 6;
  int node = blockIdx.x * 4 + wv;
  if (node >= NN) return;
  int lane = threadIdx.x & 63;
  int h = lane & 7;
  int sub = lane >> 3;
  int beg = offs[node], end = offs[node + 1];
  float edst = ed[node * NHEADS + h];
  int kb = beg;
  int iA = kb + (lane & 7); if (iA > end - 1) iA = end - 1;
  int vt = gld32i(nbr + iA);
  int vtN = 0;
  if (kb + 8 < end) {
    int iB = kb + 8 + (lane & 7); if (iB > end - 1) iB = end - 1;
    vtN = gld32i(nbr + iB);
  }
  VMCNT0();
  int se[8];
  #pragma unroll
  for (int e = 0; e < 8; e++) se[e] = __shfl(vt, e);
  float esv;
  {
    int sv = __shfl(vt, sub);
    esv = gld32f(es + (size_t)sv * NHEADS + h);
  }
  VMCNT0();
  float m = -1e30f, z = 0.f;
  float acc[8] = {};
  while (true) {
    int cnt = end - kb; if (cnt > 8) cnt = 8;
    u32x2 r[8];
    #pragma unroll
    for (int e = 0; e < 8; e++)
      if (e < cnt) r[e] = gld64(h2f8 + (size_t)se[e] * (NHEADS * NCLASS) + (lane << 3));
    bool more = kb + 8 < end, more2 = kb + 16 < end;
    int vt2 = 0;
    if (more2) {
      int iC = kb + 16 + (lane & 7); if (iC > end - 1) iC = end - 1;
      vt2 = gld32i(nbr + iC);
    }
    float esvN = 0.f;
    if (more) {
      int svN = __shfl(vtN, sub);
      esvN = gld32f(es + (size_t)svN * NHEADS + h);
    }
    // coef phase (overlaps in-flight gathers)
    float ar = esv + edst;
    ar = (ar > 0.f) ? ar : 0.2f * ar;
    float a = (kb + sub < end) ? ar : -1e30f;
    float gm = a;
    #pragma unroll
    for (int o = 8; o < 64; o <<= 1) gm = fmaxf(gm, __shfl_xor(gm, o));
    float mn = fmaxf(m, gm);
    float ee = __expf(a - mn);
    float zg = ee;
    #pragma unroll
    for (int o = 8; o < 64; o <<= 1) zg += __shfl_xor(zg, o);
    float sc = __expf(m - mn);
    z = z * sc + zg;
    m = mn;
    cs[wv][lane] = ee;  // per-wave staging, no barrier needed
    VMCNT0();
    // rescale + consume (fp8 -> f32 via v_cvt_pk_f32_fp8)
    #pragma unroll
    for (int hh = 0; hh < 8; hh++) acc[hh] *= __shfl(sc, hh);
    #pragma unroll
    for (int e = 0; e < 8; e++) {
      if (e < cnt) {
        float4 cA = *(const float4*)&cs[wv][e * 8];
        float4 cB = *(const float4*)&cs[wv][e * 8 + 4];
        f32x2 q0 = __builtin_amdgcn_cvt_pk_f32_fp8((int)r[e][0], false);
        f32x2 q1 = __builtin_amdgcn_cvt_pk_f32_fp8((int)r[e][0], true);
        f32x2 q2 = __builtin_amdgcn_cvt_pk_f32_fp8((int)r[e][1], false);
        f32x2 q3 = __builtin_amdgcn_cvt_pk_f32_fp8((int)r[e][1], true);
        acc[0] += cA.x * q0.x;
        acc[1] += cA.y * q0.y;
        acc[2] += cA.z * q1.x;
        acc[3] += cA.w * q1.y;
        acc[4] += cB.x * q2.x;
        acc[5] += cB.y * q2.y;
        acc[6] += cB.z * q3.x;
        acc[7] += cB.w * q3.y;
      }
    }
    if (!more) break;
    kb += 8;
    #pragma unroll
    for (int e = 0; e < 8; e++) se[e] = __shfl(vtN, e);
    esv = esvN;
    vtN = vt2;
  }
  float inv = 1.f / z;
  float val = 0.f;
  #pragma unroll
  for (int hh = 0; hh < 8; hh++) val += acc[hh] * __shfl(inv, hh);
  val = val * 0.125f + b2[lane];
  float mx = val;
  #pragma unroll
  for (int o = 32; o > 0; o >>= 1) mx = fmaxf(mx, __shfl_xor(mx, o));
  float ex = __expf(val - mx);
  float sm = ex;
  #pragma unroll
  for (int o = 32; o > 0; o >>= 1) sm += __shfl_xor(sm, o);
  out[(size_t)node * NCLASS + lane] = val - mx - __logf(sm);
}

// ---------------- launch ----------------
extern "C" void kernel_launch(void* const* d_in, const int* in_sizes, int n_in,
                              void* d_out, int out_size, void* d_ws, size_t ws_size,
                              hipStream_t stream) {
  const float* x   = (const float*)d_in[0];
  const int* eidx  = (const int*)d_in[1];
  const float* W1  = (const float*)d_in[2];
  const float* a1s = (const float*)d_in[3];
  const float* a1d = (const float*)d_in[4];
  const float* b1  = (const float*)d_in[5];
  const float* W2  = (const float*)d_in[6];
  const float* a2s = (const float*)d_in[7];
  const float* a2d = (const float*)d_in[8];
  const float* b2  = (const float*)d_in[9];
  const int E0 = in_sizes[1] / 2;
  const int* esrc = eidx;
  const int* edst = eidx + E0;
  const int E = E0 + NN;

  char* w = (char*)d_ws;
  auto carve = [&](size_t bytes) {
    void* p = (void*)w;
    w += (bytes + 255) & ~(size_t)255;
    return p;
  };
  int* deg      = (int*)carve((size_t)NN * 4);
  int* offs     = (int*)carve((size_t)(NN + 1) * 4);
  int* cursor   = (int*)carve((size_t)NN * 4);
  int* nbr      = (int*)carve((size_t)E * 4);
  int* bsum     = (int*)carve((size_t)64 * 4);
  int* bbase    = (int*)carve((size_t)64 * 4);
  float* es1    = (float*)carve((size_t)NN * NHEADS * 4);
  float* ed1    = (float*)carve((size_t)NN * NHEADS * 4);
  unsigned short* W1t   = (unsigned short*)carve((size_t)NF * NHID * 2);
  unsigned short* W2t   = (unsigned short*)carve((size_t)NHID * NHEADS * NCLASS * 2);
  unsigned short* h1b   = (unsigned short*)carve((size_t)NN * NHID * 2);
  unsigned short* out1b = (unsigned short*)carve((size_t)NN * NHID * 2);
  unsigned char* h1f8   = (unsigned char*)carve((size_t)NN * NHID);
  unsigned char* h2f8   = (unsigned char*)carve((size_t)NN * NHEADS * NCLASS);

  // CSR build (parallel scan)
  k_init_deg<<<(NN + 255) / 256, 256, 0, stream>>>(deg);
  k_count<<<(E0 + 255) / 256, 256, 0, stream>>>(edst, E0, deg);
  k_scanA<<<SCAN_NBLK, 256, 0, stream>>>(deg, offs, bsum);
  k_scanB<<<1, 64, 0, stream>>>(bsum, bbase, offs, SCAN_NBLK);
  k_scanC<<<SCAN_NBLK, 256, 0, stream>>>(offs, cursor, bbase);
  k_scatter<<<(E0 + NN + 255) / 256, 256, 0, stream>>>(esrc, edst, E0, cursor, nbr);

  // weight casts
  k_castWt<<<(NF * NHID + 255) / 256, 256, 0, stream>>>(W1, W1t, NF, NHID);
  k_castWt_perm<<<(NHID * NHEADS * NCLASS + 255) / 256, 256, 0, stream>>>(W2, W2t, NHID);

  // layer 1 (GEMM reads f32 x directly; writes bf16 for escore + fp8 for the gather)
  k_gemm_f32a_dual<<<dim3((NN + 63) / 64, NHID / 256), 256, 0, stream>>>(
      x, W1t, h1b, h1f8, NN, NF, NHID);
  k_escore_c<32><<<(NN * NHEADS + 255) / 256, 256, 0, stream>>>(h1b, a1s, a1d, es1, ed1);
  k_agg1f<<<(NN + 3) / 4, 256, 0, stream>>>(offs, nbr, h1f8, es1, ed1, b1, out1b);

  // layer 2 (GEMM writes fp8 directly; escore reads fp8)
  k_gemm_bf8<<<dim3((NN + 63) / 64, (NHEADS * NCLASS) / 256), 256, 0, stream>>>(
      out1b, W2t, h2f8, NN, NHID, NHEADS * NCLASS);
  k_escore_p8<<<(NN * NHEADS + 255) / 256, 256, 0, stream>>>(h2f8, a2s, a2d, es1, ed1);
  k_agg2f<<<(NN + 3) / 4, 256, 0, stream>>>(offs, nbr, h2f8, es1, ed1, b2,
                                            (float*)d_out);
}